// Round 7
// baseline (221.449 us; speedup 1.0000x reference)
//
#include <hip/hip_runtime.h>

#define N_NODES 100000
#define N_EDGES 500000
#define DIM 128
#define GB_E 1954      // ceil(E/256)
#define GB_N 391       // ceil(N/256)
#define GB_CVT 12500   // N*DIM/1024 per feature matrix
#define GB_G 782       // ceil(N/128) gemm tiles
#define GB_SEG 6250    // N*16/256 seg-mean blocks

typedef __attribute__((ext_vector_type(8))) short short8;   // 8 bf16 = 4 VGPRs
typedef __attribute__((ext_vector_type(4))) float f32x4;

__device__ __forceinline__ ushort f2bf(float f) {
    unsigned u = __float_as_uint(f);
    u += 0x7FFF + ((u >> 16) & 1);   // round-to-nearest-even
    return (ushort)(u >> 16);
}
__device__ __forceinline__ float bf2f(ushort s) {
    return __uint_as_float(((unsigned)s) << 16);
}

// ================= device bodies ====================================================

__device__ __forceinline__ void build_body(const int* __restrict__ src,
                                           const int* __restrict__ dst,
                                           int* __restrict__ head,
                                           int2* __restrict__ entry, int bid) {
    int e = bid * 256 + threadIdx.x;
    if (e < N_EDGES) {
        int d = dst[e];
        int old = atomicExch(&head[d], e);
        entry[e] = make_int2(src[e], old);
    }
}

__device__ __forceinline__ void cvt_body(const float* __restrict__ in,
                                         ushort* __restrict__ out, int bid) {
    int i = (bid * 256 + threadIdx.x) * 4;
    float4 v = *reinterpret_cast<const float4*>(&in[i]);
    ushort4 u = make_ushort4(f2bf(v.x), f2bf(v.y), f2bf(v.z), f2bf(v.w));
    *reinterpret_cast<ushort4*>(&out[i]) = u;
}

// bf16 seg-mean: 16 lanes/node, each lane owns 8 feats (16B loads)
__device__ __forceinline__ void seg_body(const ushort* __restrict__ x,
                                         const int* __restrict__ head,
                                         const int2* __restrict__ entry,
                                         ushort* __restrict__ outbf, int bid) {
    int idx = bid * 256 + threadIdx.x;
    int node = idx >> 4;
    if (node >= N_NODES) return;
    int f = (idx & 15) << 3;
    float acc[8];
#pragma unroll
    for (int j = 0; j < 8; ++j) acc[j] = 0.f;
    int cnt = 0;
    int e = head[node];
    while (e >= 0) {
        int2 nd = entry[e];   // dependent 8B load, broadcast within 16-lane group
        ++cnt;
        short8 v = *reinterpret_cast<const short8*>(&x[(size_t)nd.x * DIM + f]);
#pragma unroll
        for (int j = 0; j < 8; ++j) acc[j] += bf2f((ushort)v[j]);
        e = nd.y;
    }
    float r = 1.0f / fmaxf((float)cnt, 1.0f);
    union { ushort s[8]; uint4 v; } u;
#pragma unroll
    for (int j = 0; j < 8; ++j) u.s[j] = f2bf(acc[j] * r);
    *reinterpret_cast<uint4*>(&outbf[(size_t)node * DIM + f]) = u.v;
}

__device__ __forceinline__ float smean_body(const float* __restrict__ sval,
                                            const int* __restrict__ head,
                                            const int2* __restrict__ entry, int node) {
    float a = 0.f;
    int cnt = 0;
    int e = head[node];
    while (e >= 0) {
        int2 nd = entry[e];
        ++cnt;
        a += sval[nd.x];
        e = nd.y;
    }
    return a / fmaxf((float)cnt, 1.0f);
}

// fused layer-1 MFMA GEMM + layer-2 dots (see R6; unchanged numerics)
__device__ __forceinline__ void gemm_body(
    const ushort* __restrict__ Xsbf, const ushort* __restrict__ Nm,
    const ushort* __restrict__ Wsbf, const ushort* __restrict__ Wnbf,
    const float* __restrict__ bs, const float* __restrict__ bn,
    const float* __restrict__ w2a, const float* __restrict__ w2b,
    float* __restrict__ dself, float* __restrict__ dcross, int blk) {
    __shared__ ushort sA[128 * 64];
    __shared__ ushort sB[128 * 64];
    __shared__ float pS[2][2][128];

    const int tid = threadIdx.x;
    const int lane = tid & 63;
    const int wid = tid >> 6;
    const int wr = wid >> 1, wc = wid & 1;
    const int lr = lane & 15, lg = lane >> 4;
    const int row0 = blk * 128;

    f32x4 acc[4][4];
#pragma unroll
    for (int i = 0; i < 4; ++i)
#pragma unroll
        for (int j = 0; j < 4; ++j) acc[i][j] = (f32x4){0.f, 0.f, 0.f, 0.f};

    const int r = tid >> 1;
    const int hh = tid & 1;
    const int grow = row0 + r;
    const int swzr = (r & 7) << 4;

    for (int kb = 0; kb < 256; kb += 64) {
        const int kg = kb & 127;
        const bool self = (kb < 128);
        __syncthreads();
        {
            const uint4* g = reinterpret_cast<const uint4*>(self ? Xsbf : Nm);
#pragma unroll
            for (int q = 0; q < 4; ++q) {
                uint4 v = make_uint4(0, 0, 0, 0);
                if (grow < N_NODES)
                    v = g[((size_t)grow * DIM + kg + hh * 32 + q * 8) >> 3];
                int byte = (hh * 64 + q * 16) ^ swzr;
                *reinterpret_cast<uint4*>(&sA[r * 64 + (byte >> 1)]) = v;
            }
        }
        {
            const uint4* g = reinterpret_cast<const uint4*>(self ? Wsbf : Wnbf);
#pragma unroll
            for (int q = 0; q < 4; ++q) {
                uint4 v = g[(r * DIM + kg + hh * 32 + q * 8) >> 3];
                int byte = (hh * 64 + q * 16) ^ swzr;
                *reinterpret_cast<uint4*>(&sB[r * 64 + (byte >> 1)]) = v;
            }
        }
        __syncthreads();
#pragma unroll
        for (int ks = 0; ks < 2; ++ks) {
            short8 a[4], b[4];
#pragma unroll
            for (int fm = 0; fm < 4; ++fm) {
                int rr = wr * 64 + fm * 16 + lr;
                int byte = (ks * 64 + lg * 16) ^ ((rr & 7) << 4);
                a[fm] = *reinterpret_cast<const short8*>(&sA[rr * 64 + (byte >> 1)]);
            }
#pragma unroll
            for (int fn = 0; fn < 4; ++fn) {
                int cc = wc * 64 + fn * 16 + lr;
                int byte = (ks * 64 + lg * 16) ^ ((cc & 7) << 4);
                b[fn] = *reinterpret_cast<const short8*>(&sB[cc * 64 + (byte >> 1)]);
            }
#pragma unroll
            for (int fm = 0; fm < 4; ++fm)
#pragma unroll
                for (int fn = 0; fn < 4; ++fn)
                    acc[fm][fn] = __builtin_amdgcn_mfma_f32_16x16x32_bf16(
                        a[fm], b[fn], acc[fm][fn], 0, 0, 0);
        }
    }

    float bias[4], wa[4], wb[4];
#pragma unroll
    for (int fn = 0; fn < 4; ++fn) {
        int c = wc * 64 + fn * 16 + lr;
        bias[fn] = bs[c] + bn[c];
        wa[fn] = w2a[c];
        wb[fn] = w2b[c];
    }
#pragma unroll
    for (int fm = 0; fm < 4; ++fm) {
#pragma unroll
        for (int reg = 0; reg < 4; ++reg) {
            float pa = 0.f, pb = 0.f;
#pragma unroll
            for (int fn = 0; fn < 4; ++fn) {
                float h = fmaxf(acc[fm][fn][reg] + bias[fn], 0.f);
                pa = fmaf(h, wa[fn], pa);
                pb = fmaf(h, wb[fn], pb);
            }
#pragma unroll
            for (int m = 1; m < 16; m <<= 1) {
                pa += __shfl_xor(pa, m);
                pb += __shfl_xor(pb, m);
            }
            if (lr == 0) {
                int rloc = wr * 64 + fm * 16 + lg * 4 + reg;   // C/D row=(lane>>4)*4+reg
                pS[wc][0][rloc] = pa;
                pS[wc][1][rloc] = pb;
            }
        }
    }
    __syncthreads();
    if (tid < 128) {
        int go = row0 + tid;
        if (go < N_NODES) {
            dself[go] = pS[0][0][tid] + pS[1][0][tid];
            dcross[go] = pS[0][1][tid] + pS[1][1][tid];
        }
    }
}

// ================= kernels ==========================================================

// fatA: build both lists (atomic-bound) || weight cvt || feature cvt (BW-bound)
__global__ __launch_bounds__(256) void fatA_kernel(
    const int* __restrict__ sp, const int* __restrict__ dp,
    const int* __restrict__ sb, const int* __restrict__ db,
    int* __restrict__ head2, int2* __restrict__ entry2,
    const float* __restrict__ w0, const float* __restrict__ w1,
    const float* __restrict__ w2, const float* __restrict__ w3,
    ushort* __restrict__ o0, ushort* __restrict__ o1,
    ushort* __restrict__ o2, ushort* __restrict__ o3,
    const float* __restrict__ xu, const float* __restrict__ xt,
    ushort* __restrict__ xbf_u, ushort* __restrict__ xbf_t) {
    int bid = blockIdx.x;
    if (bid < 2 * GB_E) {
        int rel = (bid >= GB_E);
        build_body(rel ? sb : sp, rel ? db : dp, head2 + (size_t)rel * N_NODES,
                   entry2 + (size_t)rel * N_EDGES, bid - rel * GB_E);
    } else if (bid < 2 * GB_E + 64) {
        int b = bid - 2 * GB_E;
        int a = b >> 4;
        const float* in = (a == 0) ? w0 : (a == 1) ? w1 : (a == 2) ? w2 : w3;
        ushort* out = (a == 0) ? o0 : (a == 1) ? o1 : (a == 2) ? o2 : o3;
        cvt_body(in, out, b & 15);
    } else {
        int b = bid - 2 * GB_E - 64;
        int which = (b >= GB_CVT);
        cvt_body(which ? xt : xu, which ? xbf_t : xbf_u, b - which * GB_CVT);
    }
}

// seg0: neigh-mean rel0 (standalone; depends on all of fatA)
__global__ __launch_bounds__(256) void seg_only_kernel(
    const ushort* __restrict__ x, const int* __restrict__ head,
    const int2* __restrict__ entry, ushort* __restrict__ outbf) {
    seg_body(x, head, entry, outbf, blockIdx.x);
}

// fatB: gemm rel0 (MFMA-bound) || seg-mean rel1 (gather-bound) — independent
__global__ __launch_bounds__(256) void fatB_kernel(
    const ushort* __restrict__ xbf_t, const ushort* __restrict__ nbf0,
    const ushort* __restrict__ wbf_ps, const ushort* __restrict__ wbf_pn,
    const float* __restrict__ b1ps, const float* __restrict__ b1pn,
    const float* __restrict__ w2ps, const float* __restrict__ w2bn,
    float* __restrict__ dself_t, float* __restrict__ scross_t,
    const int* __restrict__ head_pb, const int2* __restrict__ ent_pb,
    ushort* __restrict__ nbf1) {
    int bid = blockIdx.x;
    if (bid < GB_G)
        gemm_body(xbf_t, nbf0, wbf_ps, wbf_pn, b1ps, b1pn, w2ps, w2bn,
                  dself_t, scross_t, bid);
    else
        seg_body(xbf_t, head_pb, ent_pb, nbf1, bid - GB_G);
}

// fatC: gemm rel1 || user-side scalar traversal (reads only fatB outputs)
__global__ __launch_bounds__(256) void fatC_kernel(
    const ushort* __restrict__ xbf_u, const ushort* __restrict__ nbf1,
    const ushort* __restrict__ wbf_bs, const ushort* __restrict__ wbf_bn,
    const float* __restrict__ b1bs, const float* __restrict__ b1bn,
    const float* __restrict__ w2bs, const float* __restrict__ w2pn,
    float* __restrict__ dself_u, float* __restrict__ scross_u,
    const float* __restrict__ scross_t,
    const int* __restrict__ head_pb, const int2* __restrict__ ent_pb,
    float* __restrict__ smean_u) {
    int bid = blockIdx.x;
    if (bid < GB_G) {
        gemm_body(xbf_u, nbf1, wbf_bs, wbf_bn, b1bs, b1bn, w2bs, w2pn,
                  dself_u, scross_u, bid);
    } else {
        int i = (bid - GB_G) * 256 + threadIdx.x;
        if (i < N_NODES) smean_u[i] = smean_body(scross_t, head_pb, ent_pb, i);
    }
}

// tail: tweet-side traversal (needs gemm1's scross_u) + assemble both outputs
__global__ __launch_bounds__(256) void tail_kernel(
    const float* __restrict__ dself_u, const float* __restrict__ smean_u,
    const float* __restrict__ dself_t, const float* __restrict__ scross_u,
    const int* __restrict__ head_posts, const int2* __restrict__ ent_posts,
    const float* __restrict__ b2bs, const float* __restrict__ b2bn,
    const float* __restrict__ b2ps, const float* __restrict__ b2pn,
    float* __restrict__ out) {
    int i = blockIdx.x * 256 + threadIdx.x;
    if (i >= N_NODES) return;
    out[N_NODES + i] = dself_t[i] + smean_body(scross_u, head_posts, ent_posts, i)
                       + b2ps[0] + b2pn[0];
    out[i] = dself_u[i] + smean_u[i] + b2bs[0] + b2bn[0];
}

// -------- f32 fallback kernels (small-ws safety) --------

__global__ __launch_bounds__(256) void cvtw_kernel(
    const float* __restrict__ w0, const float* __restrict__ w1,
    const float* __restrict__ w2, const float* __restrict__ w3,
    ushort* __restrict__ o0, ushort* __restrict__ o1,
    ushort* __restrict__ o2, ushort* __restrict__ o3) {
    int a = blockIdx.y;
    const float* in = (a == 0) ? w0 : (a == 1) ? w1 : (a == 2) ? w2 : w3;
    ushort* out = (a == 0) ? o0 : (a == 1) ? o1 : (a == 2) ? o2 : o3;
    cvt_body(in, out, blockIdx.x);
}

__global__ __launch_bounds__(256) void build_lists2_kernel(
    const int* __restrict__ s0, const int* __restrict__ d0,
    const int* __restrict__ s1, const int* __restrict__ d1,
    int* __restrict__ head2, int2* __restrict__ entry2) {
    const int rel = blockIdx.y;
    build_body(rel ? s1 : s0, rel ? d1 : d0, head2 + (size_t)rel * N_NODES,
               entry2 + (size_t)rel * N_EDGES, blockIdx.x);
}

__global__ __launch_bounds__(256) void seg_mean_f32_list_kernel(
    const float* __restrict__ x, const int* __restrict__ head,
    const int2* __restrict__ entry, ushort* __restrict__ outbf) {
    int idx = blockIdx.x * 256 + threadIdx.x;
    int node = idx >> 5;
    if (node >= N_NODES) return;
    int f = (idx & 31) << 2;
    float4 acc = make_float4(0.f, 0.f, 0.f, 0.f);
    int cnt = 0;
    int e = head[node];
    while (e >= 0) {
        int2 nd = entry[e];
        ++cnt;
        float4 v = *reinterpret_cast<const float4*>(&x[(size_t)nd.x * DIM + f]);
        acc.x += v.x; acc.y += v.y; acc.z += v.z; acc.w += v.w;
        e = nd.y;
    }
    float r = 1.0f / fmaxf((float)cnt, 1.0f);
    ushort4 u = make_ushort4(f2bf(acc.x * r), f2bf(acc.y * r),
                             f2bf(acc.z * r), f2bf(acc.w * r));
    *reinterpret_cast<ushort4*>(&outbf[node * DIM + f]) = u;
}

__global__ __launch_bounds__(256) void gemm_mfma_f32_kernel(
    const float* __restrict__ Xs, const ushort* __restrict__ Nm,
    const ushort* __restrict__ Wsbf, const ushort* __restrict__ Wnbf,
    const float* __restrict__ bs, const float* __restrict__ bn,
    const float* __restrict__ w2a, const float* __restrict__ w2b,
    float* __restrict__ dself, float* __restrict__ dcross) {
    __shared__ ushort sA[128 * 64];
    __shared__ ushort sB[128 * 64];
    __shared__ float pS[2][2][128];

    const int tid = threadIdx.x;
    const int lane = tid & 63;
    const int wid = tid >> 6;
    const int wr = wid >> 1, wc = wid & 1;
    const int lr = lane & 15, lg = lane >> 4;
    const int row0 = blockIdx.x * 128;

    f32x4 acc[4][4];
#pragma unroll
    for (int i = 0; i < 4; ++i)
#pragma unroll
        for (int j = 0; j < 4; ++j) acc[i][j] = (f32x4){0.f, 0.f, 0.f, 0.f};

    const int r = tid >> 1;
    const int hh = tid & 1;
    const int grow = row0 + r;
    const int swzr = (r & 7) << 4;

    for (int kb = 0; kb < 256; kb += 64) {
        const int kg = kb & 127;
        const bool self = (kb < 128);
        __syncthreads();
        if (self) {
            const float4* g = reinterpret_cast<const float4*>(Xs);
#pragma unroll
            for (int q = 0; q < 4; ++q) {
                float4 v0 = make_float4(0.f, 0.f, 0.f, 0.f), v1 = v0;
                if (grow < N_NODES) {
                    size_t bi = ((size_t)grow * DIM + kg + hh * 32 + q * 8) >> 2;
                    v0 = g[bi];
                    v1 = g[bi + 1];
                }
                union { ushort s[8]; uint4 v; } u;
                u.s[0] = f2bf(v0.x); u.s[1] = f2bf(v0.y);
                u.s[2] = f2bf(v0.z); u.s[3] = f2bf(v0.w);
                u.s[4] = f2bf(v1.x); u.s[5] = f2bf(v1.y);
                u.s[6] = f2bf(v1.z); u.s[7] = f2bf(v1.w);
                int byte = (hh * 64 + q * 16) ^ swzr;
                *reinterpret_cast<uint4*>(&sA[r * 64 + (byte >> 1)]) = u.v;
            }
        } else {
            const uint4* g = reinterpret_cast<const uint4*>(Nm);
#pragma unroll
            for (int q = 0; q < 4; ++q) {
                uint4 v = make_uint4(0, 0, 0, 0);
                if (grow < N_NODES)
                    v = g[((size_t)grow * DIM + kg + hh * 32 + q * 8) >> 3];
                int byte = (hh * 64 + q * 16) ^ swzr;
                *reinterpret_cast<uint4*>(&sA[r * 64 + (byte >> 1)]) = v;
            }
        }
        {
            const uint4* g = reinterpret_cast<const uint4*>(self ? Wsbf : Wnbf);
#pragma unroll
            for (int q = 0; q < 4; ++q) {
                uint4 v = g[(r * DIM + kg + hh * 32 + q * 8) >> 3];
                int byte = (hh * 64 + q * 16) ^ swzr;
                *reinterpret_cast<uint4*>(&sB[r * 64 + (byte >> 1)]) = v;
            }
        }
        __syncthreads();
#pragma unroll
        for (int ks = 0; ks < 2; ++ks) {
            short8 a[4], b[4];
#pragma unroll
            for (int fm = 0; fm < 4; ++fm) {
                int rr = wr * 64 + fm * 16 + lr;
                int byte = (ks * 64 + lg * 16) ^ ((rr & 7) << 4);
                a[fm] = *reinterpret_cast<const short8*>(&sA[rr * 64 + (byte >> 1)]);
            }
#pragma unroll
            for (int fn = 0; fn < 4; ++fn) {
                int cc = wc * 64 + fn * 16 + lr;
                int byte = (ks * 64 + lg * 16) ^ ((cc & 7) << 4);
                b[fn] = *reinterpret_cast<const short8*>(&sB[cc * 64 + (byte >> 1)]);
            }
#pragma unroll
            for (int fm = 0; fm < 4; ++fm)
#pragma unroll
                for (int fn = 0; fn < 4; ++fn)
                    acc[fm][fn] = __builtin_amdgcn_mfma_f32_16x16x32_bf16(
                        a[fm], b[fn], acc[fm][fn], 0, 0, 0);
        }
    }

    float bias[4], wa[4], wb[4];
#pragma unroll
    for (int fn = 0; fn < 4; ++fn) {
        int c = wc * 64 + fn * 16 + lr;
        bias[fn] = bs[c] + bn[c];
        wa[fn] = w2a[c];
        wb[fn] = w2b[c];
    }
#pragma unroll
    for (int fm = 0; fm < 4; ++fm) {
#pragma unroll
        for (int reg = 0; reg < 4; ++reg) {
            float pa = 0.f, pb = 0.f;
#pragma unroll
            for (int fn = 0; fn < 4; ++fn) {
                float h = fmaxf(acc[fm][fn][reg] + bias[fn], 0.f);
                pa = fmaf(h, wa[fn], pa);
                pb = fmaf(h, wb[fn], pb);
            }
#pragma unroll
            for (int m = 1; m < 16; m <<= 1) {
                pa += __shfl_xor(pa, m);
                pb += __shfl_xor(pb, m);
            }
            if (lr == 0) {
                int rloc = wr * 64 + fm * 16 + lg * 4 + reg;
                pS[wc][0][rloc] = pa;
                pS[wc][1][rloc] = pb;
            }
        }
    }
    __syncthreads();
    if (tid < 128) {
        int go = row0 + tid;
        if (go < N_NODES) {
            dself[go] = pS[0][0][tid] + pS[1][0][tid];
            dcross[go] = pS[0][1][tid] + pS[1][1][tid];
        }
    }
}

__global__ __launch_bounds__(256) void scalar_finalize_kernel(
    const float* __restrict__ dself_u, const float* __restrict__ dself_t,
    const float* __restrict__ scross_u, const float* __restrict__ scross_t,
    const int* __restrict__ head2, const int2* __restrict__ entry2,
    const float* __restrict__ b2bs, const float* __restrict__ b2bn,
    const float* __restrict__ b2ps, const float* __restrict__ b2pn,
    float* __restrict__ out) {
    int i = blockIdx.x * 256 + threadIdx.x;
    if (i >= N_NODES) return;
    out[N_NODES + i] = dself_t[i] + smean_body(scross_u, head2, entry2, i)
                       + b2ps[0] + b2pn[0];
    out[i] = dself_u[i] + smean_body(scross_t, head2 + N_NODES, entry2 + N_EDGES, i)
             + b2bs[0] + b2bn[0];
}

// ===================================================================================

extern "C" void kernel_launch(void* const* d_in, const int* in_sizes, int n_in,
                              void* d_out, int out_size, void* d_ws, size_t ws_size,
                              hipStream_t stream) {
    const float* x_user  = (const float*)d_in[0];
    const float* x_tweet = (const float*)d_in[1];
    const float* w1ps = (const float*)d_in[2];  const float* b1ps = (const float*)d_in[3];
    const float* w1pn = (const float*)d_in[4];  const float* b1pn = (const float*)d_in[5];
    const float* w1bs = (const float*)d_in[6];  const float* b1bs = (const float*)d_in[7];
    const float* w1bn = (const float*)d_in[8];  const float* b1bn = (const float*)d_in[9];
    const float* w2ps = (const float*)d_in[10]; const float* b2ps = (const float*)d_in[11];
    const float* w2pn = (const float*)d_in[12]; const float* b2pn = (const float*)d_in[13];
    const float* w2bs = (const float*)d_in[14]; const float* b2bs = (const float*)d_in[15];
    const float* w2bn = (const float*)d_in[16]; const float* b2bn = (const float*)d_in[17];
    const int* src_posts = (const int*)d_in[18];
    const int* dst_posts = (const int*)d_in[19];
    const int* src_pb    = (const int*)d_in[20];
    const int* dst_pb    = (const int*)d_in[21];
    float* out = (float*)d_out;

    // ---- workspace layout (16B aligned regions) ----
    char* wsb = (char*)d_ws;
    ushort* nbf0    = (ushort*)wsb;   wsb += (size_t)N_NODES * DIM * 2;      // 25.6 MB
    int* head2      = (int*)wsb;      wsb += (size_t)2 * N_NODES * 4;        //  0.8 MB
    int2* entry2    = (int2*)wsb;     wsb += (size_t)2 * N_EDGES * 8;        //  8.0 MB
    ushort* wbf_ps  = (ushort*)wsb;   wsb += (size_t)DIM * DIM * 2;
    ushort* wbf_pn  = (ushort*)wsb;   wsb += (size_t)DIM * DIM * 2;
    ushort* wbf_bs  = (ushort*)wsb;   wsb += (size_t)DIM * DIM * 2;
    ushort* wbf_bn  = (ushort*)wsb;   wsb += (size_t)DIM * DIM * 2;
    float* dself_t  = (float*)wsb;    wsb += (size_t)N_NODES * 4;
    float* scross_t = (float*)wsb;    wsb += (size_t)N_NODES * 4;
    float* dself_u  = (float*)wsb;    wsb += (size_t)N_NODES * 4;
    float* scross_u = (float*)wsb;    wsb += (size_t)N_NODES * 4;
    float* smean_u  = (float*)wsb;    wsb += (size_t)N_NODES * 4;
    // bf16 regions last so the fallback footprint stays small
    ushort* nbf1    = (ushort*)wsb;   wsb += (size_t)N_NODES * DIM * 2;      // 25.6 MB
    ushort* xbf_u   = (ushort*)wsb;   wsb += (size_t)N_NODES * DIM * 2;      // 25.6 MB
    ushort* xbf_t   = (ushort*)wsb;   wsb += (size_t)N_NODES * DIM * 2;      // 25.6 MB
    const bool use_bf = ((size_t)(wsb - (char*)d_ws) <= ws_size);

    const int* head_posts = head2;
    const int* head_pb    = head2 + N_NODES;
    const int2* ent_posts = entry2;
    const int2* ent_pb    = entry2 + N_EDGES;

    hipMemsetAsync(head2, 0xFF, (size_t)2 * N_NODES * sizeof(int), stream);

    if (!use_bf) {
        cvtw_kernel<<<dim3(16, 4), 256, 0, stream>>>(w1ps, w1pn, w1bs, w1bn,
                                                     wbf_ps, wbf_pn, wbf_bs, wbf_bn);
        build_lists2_kernel<<<dim3(GB_E, 2), 256, 0, stream>>>(
            src_posts, dst_posts, src_pb, dst_pb, head2, entry2);
        seg_mean_f32_list_kernel<<<(N_NODES * 32 + 255) / 256, 256, 0, stream>>>(
            x_user, head_posts, ent_posts, nbf0);
        gemm_mfma_f32_kernel<<<GB_G, 256, 0, stream>>>(x_tweet, nbf0, wbf_ps, wbf_pn,
                                                       b1ps, b1pn, w2ps, w2bn,
                                                       dself_t, scross_t);
        seg_mean_f32_list_kernel<<<(N_NODES * 32 + 255) / 256, 256, 0, stream>>>(
            x_tweet, head_pb, ent_pb, nbf0);
        gemm_mfma_f32_kernel<<<GB_G, 256, 0, stream>>>(x_user, nbf0, wbf_bs, wbf_bn,
                                                       b1bs, b1bn, w2bs, w2pn,
                                                       dself_u, scross_u);
        scalar_finalize_kernel<<<GB_N, 256, 0, stream>>>(dself_u, dself_t,
                                                         scross_u, scross_t,
                                                         head2, entry2,
                                                         b2bs, b2bn, b2ps, b2pn, out);
        return;
    }

    // -------- bf16 fast path with overlap fusion --------
    fatA_kernel<<<2 * GB_E + 64 + 2 * GB_CVT, 256, 0, stream>>>(
        src_posts, dst_posts, src_pb, dst_pb, head2, entry2,
        w1ps, w1pn, w1bs, w1bn, wbf_ps, wbf_pn, wbf_bs, wbf_bn,
        x_user, x_tweet, xbf_u, xbf_t);

    seg_only_kernel<<<GB_SEG, 256, 0, stream>>>(xbf_u, head_posts, ent_posts, nbf0);

    fatB_kernel<<<GB_G + GB_SEG, 256, 0, stream>>>(
        xbf_t, nbf0, wbf_ps, wbf_pn, b1ps, b1pn, w2ps, w2bn,
        dself_t, scross_t, head_pb, ent_pb, nbf1);

    fatC_kernel<<<GB_G + GB_N, 256, 0, stream>>>(
        xbf_u, nbf1, wbf_bs, wbf_bn, b1bs, b1bn, w2bs, w2pn,
        dself_u, scross_u, scross_t, head_pb, ent_pb, smean_u);

    tail_kernel<<<GB_N, 256, 0, stream>>>(dself_u, smean_u, dself_t, scross_u,
                                          head_posts, ent_posts,
                                          b2bs, b2bn, b2ps, b2pn, out);
}

// Round 8
// 218.465 us; speedup vs baseline: 1.0137x; 1.0137x over previous
//
#include <hip/hip_runtime.h>

#define N_NODES 100000
#define N_EDGES 500000
#define DIM 128
#define GB_E 1954      // ceil(E/256)
#define GB_N 391       // ceil(N/256)
#define GB_CVT 12500   // N*DIM/1024 per feature matrix
#define GB_G 782       // ceil(N/128) gemm tiles
#define GB_SEG 6250    // N*16/256 seg-mean blocks

typedef __attribute__((ext_vector_type(8))) short short8;   // 8 bf16 = 4 VGPRs
typedef __attribute__((ext_vector_type(4))) float f32x4;

__device__ __forceinline__ ushort f2bf(float f) {
    unsigned u = __float_as_uint(f);
    u += 0x7FFF + ((u >> 16) & 1);   // round-to-nearest-even
    return (ushort)(u >> 16);
}
__device__ __forceinline__ float bf2f(ushort s) {
    return __uint_as_float(((unsigned)s) << 16);
}

// ================= device bodies ====================================================

__device__ __forceinline__ void build_body(const int* __restrict__ src,
                                           const int* __restrict__ dst,
                                           int* __restrict__ head,
                                           int2* __restrict__ entry, int bid) {
    int e = bid * 256 + threadIdx.x;
    if (e < N_EDGES) {
        int d = dst[e];
        int old = atomicExch(&head[d], e);
        entry[e] = make_int2(src[e], old);
    }
}

__device__ __forceinline__ void cvt_body(const float* __restrict__ in,
                                         ushort* __restrict__ out, int bid) {
    int i = (bid * 256 + threadIdx.x) * 4;
    float4 v = *reinterpret_cast<const float4*>(&in[i]);
    ushort4 u = make_ushort4(f2bf(v.x), f2bf(v.y), f2bf(v.z), f2bf(v.w));
    *reinterpret_cast<ushort4*>(&out[i]) = u;
}

// bf16 seg-mean: 16 lanes/node, each lane owns 8 feats (16B loads)
__device__ __forceinline__ void seg_body(const ushort* __restrict__ x,
                                         const int* __restrict__ head,
                                         const int2* __restrict__ entry,
                                         ushort* __restrict__ outbf, int bid) {
    int idx = bid * 256 + threadIdx.x;
    int node = idx >> 4;
    if (node >= N_NODES) return;
    int f = (idx & 15) << 3;
    float acc[8];
#pragma unroll
    for (int j = 0; j < 8; ++j) acc[j] = 0.f;
    int cnt = 0;
    int e = head[node];
    while (e >= 0) {
        int2 nd = entry[e];   // dependent 8B load, broadcast within 16-lane group
        ++cnt;
        short8 v = *reinterpret_cast<const short8*>(&x[(size_t)nd.x * DIM + f]);
#pragma unroll
        for (int j = 0; j < 8; ++j) acc[j] += bf2f((ushort)v[j]);
        e = nd.y;
    }
    float r = 1.0f / fmaxf((float)cnt, 1.0f);
    union { ushort s[8]; uint4 v; } u;
#pragma unroll
    for (int j = 0; j < 8; ++j) u.s[j] = f2bf(acc[j] * r);
    *reinterpret_cast<uint4*>(&outbf[(size_t)node * DIM + f]) = u.v;
}

__device__ __forceinline__ float smean_body(const float* __restrict__ sval,
                                            const int* __restrict__ head,
                                            const int2* __restrict__ entry, int node) {
    float a = 0.f;
    int cnt = 0;
    int e = head[node];
    while (e >= 0) {
        int2 nd = entry[e];
        ++cnt;
        a += sval[nd.x];
        e = nd.y;
    }
    return a / fmaxf((float)cnt, 1.0f);
}

// fused layer-1 MFMA GEMM + layer-2 dots. h = relu(Xs@Ws.T+bs + Nm@Wn.T+bn);
// dself=h·w2a, dcross=h·w2b. 128x128 tile, 4 waves, K=256, BK=64, XOR-swizzled LDS.
__device__ __forceinline__ void gemm_body(
    const ushort* __restrict__ Xsbf, const ushort* __restrict__ Nm,
    const ushort* __restrict__ Wsbf, const ushort* __restrict__ Wnbf,
    const float* __restrict__ bs, const float* __restrict__ bn,
    const float* __restrict__ w2a, const float* __restrict__ w2b,
    float* __restrict__ dself, float* __restrict__ dcross, int blk) {
    __shared__ ushort sA[128 * 64];
    __shared__ ushort sB[128 * 64];
    __shared__ float pS[2][2][128];

    const int tid = threadIdx.x;
    const int lane = tid & 63;
    const int wid = tid >> 6;
    const int wr = wid >> 1, wc = wid & 1;
    const int lr = lane & 15, lg = lane >> 4;
    const int row0 = blk * 128;

    f32x4 acc[4][4];
#pragma unroll
    for (int i = 0; i < 4; ++i)
#pragma unroll
        for (int j = 0; j < 4; ++j) acc[i][j] = (f32x4){0.f, 0.f, 0.f, 0.f};

    const int r = tid >> 1;
    const int hh = tid & 1;
    const int grow = row0 + r;
    const int swzr = (r & 7) << 4;

    for (int kb = 0; kb < 256; kb += 64) {
        const int kg = kb & 127;
        const bool self = (kb < 128);
        __syncthreads();
        {
            const uint4* g = reinterpret_cast<const uint4*>(self ? Xsbf : Nm);
#pragma unroll
            for (int q = 0; q < 4; ++q) {
                uint4 v = make_uint4(0, 0, 0, 0);
                if (grow < N_NODES)
                    v = g[((size_t)grow * DIM + kg + hh * 32 + q * 8) >> 3];
                int byte = (hh * 64 + q * 16) ^ swzr;
                *reinterpret_cast<uint4*>(&sA[r * 64 + (byte >> 1)]) = v;
            }
        }
        {
            const uint4* g = reinterpret_cast<const uint4*>(self ? Wsbf : Wnbf);
#pragma unroll
            for (int q = 0; q < 4; ++q) {
                uint4 v = g[(r * DIM + kg + hh * 32 + q * 8) >> 3];
                int byte = (hh * 64 + q * 16) ^ swzr;
                *reinterpret_cast<uint4*>(&sB[r * 64 + (byte >> 1)]) = v;
            }
        }
        __syncthreads();
#pragma unroll
        for (int ks = 0; ks < 2; ++ks) {
            short8 a[4], b[4];
#pragma unroll
            for (int fm = 0; fm < 4; ++fm) {
                int rr = wr * 64 + fm * 16 + lr;
                int byte = (ks * 64 + lg * 16) ^ ((rr & 7) << 4);
                a[fm] = *reinterpret_cast<const short8*>(&sA[rr * 64 + (byte >> 1)]);
            }
#pragma unroll
            for (int fn = 0; fn < 4; ++fn) {
                int cc = wc * 64 + fn * 16 + lr;
                int byte = (ks * 64 + lg * 16) ^ ((cc & 7) << 4);
                b[fn] = *reinterpret_cast<const short8*>(&sB[cc * 64 + (byte >> 1)]);
            }
#pragma unroll
            for (int fm = 0; fm < 4; ++fm)
#pragma unroll
                for (int fn = 0; fn < 4; ++fn)
                    acc[fm][fn] = __builtin_amdgcn_mfma_f32_16x16x32_bf16(
                        a[fm], b[fn], acc[fm][fn], 0, 0, 0);
        }
    }

    float bias[4], wa[4], wb[4];
#pragma unroll
    for (int fn = 0; fn < 4; ++fn) {
        int c = wc * 64 + fn * 16 + lr;
        bias[fn] = bs[c] + bn[c];
        wa[fn] = w2a[c];
        wb[fn] = w2b[c];
    }
#pragma unroll
    for (int fm = 0; fm < 4; ++fm) {
#pragma unroll
        for (int reg = 0; reg < 4; ++reg) {
            float pa = 0.f, pb = 0.f;
#pragma unroll
            for (int fn = 0; fn < 4; ++fn) {
                float h = fmaxf(acc[fm][fn][reg] + bias[fn], 0.f);
                pa = fmaf(h, wa[fn], pa);
                pb = fmaf(h, wb[fn], pb);
            }
#pragma unroll
            for (int m = 1; m < 16; m <<= 1) {
                pa += __shfl_xor(pa, m);
                pb += __shfl_xor(pb, m);
            }
            if (lr == 0) {
                int rloc = wr * 64 + fm * 16 + lg * 4 + reg;   // C/D row=(lane>>4)*4+reg
                pS[wc][0][rloc] = pa;
                pS[wc][1][rloc] = pb;
            }
        }
    }
    __syncthreads();
    if (tid < 128) {
        int go = row0 + tid;
        if (go < N_NODES) {
            dself[go] = pS[0][0][tid] + pS[1][0][tid];
            dcross[go] = pS[0][1][tid] + pS[1][1][tid];
        }
    }
}

// ================= kernels ==========================================================

// cvt-fat: weight cvt (64 blocks) + both feature cvts (pure BW, no atomics)
__global__ __launch_bounds__(256) void cvt_fat_kernel(
    const float* __restrict__ w0, const float* __restrict__ w1,
    const float* __restrict__ w2, const float* __restrict__ w3,
    ushort* __restrict__ o0, ushort* __restrict__ o1,
    ushort* __restrict__ o2, ushort* __restrict__ o3,
    const float* __restrict__ xu, const float* __restrict__ xt,
    ushort* __restrict__ xbf_u, ushort* __restrict__ xbf_t) {
    int bid = blockIdx.x;
    if (bid < 64) {
        int a = bid >> 4;
        const float* in = (a == 0) ? w0 : (a == 1) ? w1 : (a == 2) ? w2 : w3;
        ushort* out = (a == 0) ? o0 : (a == 1) ? o1 : (a == 2) ? o2 : o3;
        cvt_body(in, out, bid & 15);
    } else {
        int b = bid - 64;
        int which = (b >= GB_CVT);
        cvt_body(which ? xt : xu, which ? xbf_t : xbf_u, b - which * GB_CVT);
    }
}

// build one relation (standalone, atomic-bound)
__global__ __launch_bounds__(256) void build1_kernel(
    const int* __restrict__ src, const int* __restrict__ dst,
    int* __restrict__ head, int2* __restrict__ entry) {
    build_body(src, dst, head, entry, blockIdx.x);
}

// fatS: build rel1 (atomic) || seg-mean rel0 (gather-latency). Independent work.
// Build blocks first so they are co-resident with seg from t=0 (full overlap).
__global__ __launch_bounds__(256) void fatS_kernel(
    const int* __restrict__ s1, const int* __restrict__ d1,
    int* __restrict__ head_pb, int2* __restrict__ ent_pb,
    const ushort* __restrict__ xbf_u, const int* __restrict__ head_posts,
    const int2* __restrict__ ent_posts, ushort* __restrict__ nbf0) {
    int bid = blockIdx.x;
    if (bid < GB_E)
        build_body(s1, d1, head_pb, ent_pb, bid);
    else
        seg_body(xbf_u, head_posts, ent_posts, nbf0, bid - GB_E);
}

// fatB: gemm rel0 (MFMA-bound) || seg-mean rel1 (gather-bound) — independent
__global__ __launch_bounds__(256) void fatB_kernel(
    const ushort* __restrict__ xbf_t, const ushort* __restrict__ nbf0,
    const ushort* __restrict__ wbf_ps, const ushort* __restrict__ wbf_pn,
    const float* __restrict__ b1ps, const float* __restrict__ b1pn,
    const float* __restrict__ w2ps, const float* __restrict__ w2bn,
    float* __restrict__ dself_t, float* __restrict__ scross_t,
    const int* __restrict__ head_pb, const int2* __restrict__ ent_pb,
    ushort* __restrict__ nbf1) {
    int bid = blockIdx.x;
    if (bid < GB_G)
        gemm_body(xbf_t, nbf0, wbf_ps, wbf_pn, b1ps, b1pn, w2ps, w2bn,
                  dself_t, scross_t, bid);
    else
        seg_body(xbf_t, head_pb, ent_pb, nbf1, bid - GB_G);
}

// fatC: gemm rel1 || user-side scalar traversal (reads only fatB outputs)
__global__ __launch_bounds__(256) void fatC_kernel(
    const ushort* __restrict__ xbf_u, const ushort* __restrict__ nbf1,
    const ushort* __restrict__ wbf_bs, const ushort* __restrict__ wbf_bn,
    const float* __restrict__ b1bs, const float* __restrict__ b1bn,
    const float* __restrict__ w2bs, const float* __restrict__ w2pn,
    float* __restrict__ dself_u, float* __restrict__ scross_u,
    const float* __restrict__ scross_t,
    const int* __restrict__ head_pb, const int2* __restrict__ ent_pb,
    float* __restrict__ smean_u) {
    int bid = blockIdx.x;
    if (bid < GB_G) {
        gemm_body(xbf_u, nbf1, wbf_bs, wbf_bn, b1bs, b1bn, w2bs, w2pn,
                  dself_u, scross_u, bid);
    } else {
        int i = (bid - GB_G) * 256 + threadIdx.x;
        if (i < N_NODES) smean_u[i] = smean_body(scross_t, head_pb, ent_pb, i);
    }
}

// tail: tweet-side traversal (needs gemm1's scross_u) + assemble both outputs
__global__ __launch_bounds__(256) void tail_kernel(
    const float* __restrict__ dself_u, const float* __restrict__ smean_u,
    const float* __restrict__ dself_t, const float* __restrict__ scross_u,
    const int* __restrict__ head_posts, const int2* __restrict__ ent_posts,
    const float* __restrict__ b2bs, const float* __restrict__ b2bn,
    const float* __restrict__ b2ps, const float* __restrict__ b2pn,
    float* __restrict__ out) {
    int i = blockIdx.x * 256 + threadIdx.x;
    if (i >= N_NODES) return;
    out[N_NODES + i] = dself_t[i] + smean_body(scross_u, head_posts, ent_posts, i)
                       + b2ps[0] + b2pn[0];
    out[i] = dself_u[i] + smean_u[i] + b2bs[0] + b2bn[0];
}

// -------- f32 fallback kernels (small-ws safety) --------

__global__ __launch_bounds__(256) void cvtw_kernel(
    const float* __restrict__ w0, const float* __restrict__ w1,
    const float* __restrict__ w2, const float* __restrict__ w3,
    ushort* __restrict__ o0, ushort* __restrict__ o1,
    ushort* __restrict__ o2, ushort* __restrict__ o3) {
    int a = blockIdx.y;
    const float* in = (a == 0) ? w0 : (a == 1) ? w1 : (a == 2) ? w2 : w3;
    ushort* out = (a == 0) ? o0 : (a == 1) ? o1 : (a == 2) ? o2 : o3;
    cvt_body(in, out, blockIdx.x);
}

__global__ __launch_bounds__(256) void build_lists2_kernel(
    const int* __restrict__ s0, const int* __restrict__ d0,
    const int* __restrict__ s1, const int* __restrict__ d1,
    int* __restrict__ head2, int2* __restrict__ entry2) {
    const int rel = blockIdx.y;
    build_body(rel ? s1 : s0, rel ? d1 : d0, head2 + (size_t)rel * N_NODES,
               entry2 + (size_t)rel * N_EDGES, blockIdx.x);
}

__global__ __launch_bounds__(256) void seg_mean_f32_list_kernel(
    const float* __restrict__ x, const int* __restrict__ head,
    const int2* __restrict__ entry, ushort* __restrict__ outbf) {
    int idx = blockIdx.x * 256 + threadIdx.x;
    int node = idx >> 5;
    if (node >= N_NODES) return;
    int f = (idx & 31) << 2;
    float4 acc = make_float4(0.f, 0.f, 0.f, 0.f);
    int cnt = 0;
    int e = head[node];
    while (e >= 0) {
        int2 nd = entry[e];
        ++cnt;
        float4 v = *reinterpret_cast<const float4*>(&x[(size_t)nd.x * DIM + f]);
        acc.x += v.x; acc.y += v.y; acc.z += v.z; acc.w += v.w;
        e = nd.y;
    }
    float r = 1.0f / fmaxf((float)cnt, 1.0f);
    ushort4 u = make_ushort4(f2bf(acc.x * r), f2bf(acc.y * r),
                             f2bf(acc.z * r), f2bf(acc.w * r));
    *reinterpret_cast<ushort4*>(&outbf[node * DIM + f]) = u;
}

__global__ __launch_bounds__(256) void gemm_mfma_f32_kernel(
    const float* __restrict__ Xs, const ushort* __restrict__ Nm,
    const ushort* __restrict__ Wsbf, const ushort* __restrict__ Wnbf,
    const float* __restrict__ bs, const float* __restrict__ bn,
    const float* __restrict__ w2a, const float* __restrict__ w2b,
    float* __restrict__ dself, float* __restrict__ dcross) {
    __shared__ ushort sA[128 * 64];
    __shared__ ushort sB[128 * 64];
    __shared__ float pS[2][2][128];

    const int tid = threadIdx.x;
    const int lane = tid & 63;
    const int wid = tid >> 6;
    const int wr = wid >> 1, wc = wid & 1;
    const int lr = lane & 15, lg = lane >> 4;
    const int row0 = blockIdx.x * 128;

    f32x4 acc[4][4];
#pragma unroll
    for (int i = 0; i < 4; ++i)
#pragma unroll
        for (int j = 0; j < 4; ++j) acc[i][j] = (f32x4){0.f, 0.f, 0.f, 0.f};

    const int r = tid >> 1;
    const int hh = tid & 1;
    const int grow = row0 + r;
    const int swzr = (r & 7) << 4;

    for (int kb = 0; kb < 256; kb += 64) {
        const int kg = kb & 127;
        const bool self = (kb < 128);
        __syncthreads();
        if (self) {
            const float4* g = reinterpret_cast<const float4*>(Xs);
#pragma unroll
            for (int q = 0; q < 4; ++q) {
                float4 v0 = make_float4(0.f, 0.f, 0.f, 0.f), v1 = v0;
                if (grow < N_NODES) {
                    size_t bi = ((size_t)grow * DIM + kg + hh * 32 + q * 8) >> 2;
                    v0 = g[bi];
                    v1 = g[bi + 1];
                }
                union { ushort s[8]; uint4 v; } u;
                u.s[0] = f2bf(v0.x); u.s[1] = f2bf(v0.y);
                u.s[2] = f2bf(v0.z); u.s[3] = f2bf(v0.w);
                u.s[4] = f2bf(v1.x); u.s[5] = f2bf(v1.y);
                u.s[6] = f2bf(v1.z); u.s[7] = f2bf(v1.w);
                int byte = (hh * 64 + q * 16) ^ swzr;
                *reinterpret_cast<uint4*>(&sA[r * 64 + (byte >> 1)]) = u.v;
            }
        } else {
            const uint4* g = reinterpret_cast<const uint4*>(Nm);
#pragma unroll
            for (int q = 0; q < 4; ++q) {
                uint4 v = make_uint4(0, 0, 0, 0);
                if (grow < N_NODES)
                    v = g[((size_t)grow * DIM + kg + hh * 32 + q * 8) >> 3];
                int byte = (hh * 64 + q * 16) ^ swzr;
                *reinterpret_cast<uint4*>(&sA[r * 64 + (byte >> 1)]) = v;
            }
        }
        {
            const uint4* g = reinterpret_cast<const uint4*>(self ? Wsbf : Wnbf);
#pragma unroll
            for (int q = 0; q < 4; ++q) {
                uint4 v = g[(r * DIM + kg + hh * 32 + q * 8) >> 3];
                int byte = (hh * 64 + q * 16) ^ swzr;
                *reinterpret_cast<uint4*>(&sB[r * 64 + (byte >> 1)]) = v;
            }
        }
        __syncthreads();
#pragma unroll
        for (int ks = 0; ks < 2; ++ks) {
            short8 a[4], b[4];
#pragma unroll
            for (int fm = 0; fm < 4; ++fm) {
                int rr = wr * 64 + fm * 16 + lr;
                int byte = (ks * 64 + lg * 16) ^ ((rr & 7) << 4);
                a[fm] = *reinterpret_cast<const short8*>(&sA[rr * 64 + (byte >> 1)]);
            }
#pragma unroll
            for (int fn = 0; fn < 4; ++fn) {
                int cc = wc * 64 + fn * 16 + lr;
                int byte = (ks * 64 + lg * 16) ^ ((cc & 7) << 4);
                b[fn] = *reinterpret_cast<const short8*>(&sB[cc * 64 + (byte >> 1)]);
            }
#pragma unroll
            for (int fm = 0; fm < 4; ++fm)
#pragma unroll
                for (int fn = 0; fn < 4; ++fn)
                    acc[fm][fn] = __builtin_amdgcn_mfma_f32_16x16x32_bf16(
                        a[fm], b[fn], acc[fm][fn], 0, 0, 0);
        }
    }

    float bias[4], wa[4], wb[4];
#pragma unroll
    for (int fn = 0; fn < 4; ++fn) {
        int c = wc * 64 + fn * 16 + lr;
        bias[fn] = bs[c] + bn[c];
        wa[fn] = w2a[c];
        wb[fn] = w2b[c];
    }
#pragma unroll
    for (int fm = 0; fm < 4; ++fm) {
#pragma unroll
        for (int reg = 0; reg < 4; ++reg) {
            float pa = 0.f, pb = 0.f;
#pragma unroll
            for (int fn = 0; fn < 4; ++fn) {
                float h = fmaxf(acc[fm][fn][reg] + bias[fn], 0.f);
                pa = fmaf(h, wa[fn], pa);
                pb = fmaf(h, wb[fn], pb);
            }
#pragma unroll
            for (int m = 1; m < 16; m <<= 1) {
                pa += __shfl_xor(pa, m);
                pb += __shfl_xor(pb, m);
            }
            if (lr == 0) {
                int rloc = wr * 64 + fm * 16 + lg * 4 + reg;
                pS[wc][0][rloc] = pa;
                pS[wc][1][rloc] = pb;
            }
        }
    }
    __syncthreads();
    if (tid < 128) {
        int go = row0 + tid;
        if (go < N_NODES) {
            dself[go] = pS[0][0][tid] + pS[1][0][tid];
            dcross[go] = pS[0][1][tid] + pS[1][1][tid];
        }
    }
}

__global__ __launch_bounds__(256) void scalar_finalize_kernel(
    const float* __restrict__ dself_u, const float* __restrict__ dself_t,
    const float* __restrict__ scross_u, const float* __restrict__ scross_t,
    const int* __restrict__ head2, const int2* __restrict__ entry2,
    const float* __restrict__ b2bs, const float* __restrict__ b2bn,
    const float* __restrict__ b2ps, const float* __restrict__ b2pn,
    float* __restrict__ out) {
    int i = blockIdx.x * 256 + threadIdx.x;
    if (i >= N_NODES) return;
    out[N_NODES + i] = dself_t[i] + smean_body(scross_u, head2, entry2, i)
                       + b2ps[0] + b2pn[0];
    out[i] = dself_u[i] + smean_body(scross_t, head2 + N_NODES, entry2 + N_EDGES, i)
             + b2bs[0] + b2bn[0];
}

// ===================================================================================

extern "C" void kernel_launch(void* const* d_in, const int* in_sizes, int n_in,
                              void* d_out, int out_size, void* d_ws, size_t ws_size,
                              hipStream_t stream) {
    const float* x_user  = (const float*)d_in[0];
    const float* x_tweet = (const float*)d_in[1];
    const float* w1ps = (const float*)d_in[2];  const float* b1ps = (const float*)d_in[3];
    const float* w1pn = (const float*)d_in[4];  const float* b1pn = (const float*)d_in[5];
    const float* w1bs = (const float*)d_in[6];  const float* b1bs = (const float*)d_in[7];
    const float* w1bn = (const float*)d_in[8];  const float* b1bn = (const float*)d_in[9];
    const float* w2ps = (const float*)d_in[10]; const float* b2ps = (const float*)d_in[11];
    const float* w2pn = (const float*)d_in[12]; const float* b2pn = (const float*)d_in[13];
    const float* w2bs = (const float*)d_in[14]; const float* b2bs = (const float*)d_in[15];
    const float* w2bn = (const float*)d_in[16]; const float* b2bn = (const float*)d_in[17];
    const int* src_posts = (const int*)d_in[18];
    const int* dst_posts = (const int*)d_in[19];
    const int* src_pb    = (const int*)d_in[20];
    const int* dst_pb    = (const int*)d_in[21];
    float* out = (float*)d_out;

    // ---- workspace layout (16B aligned regions) ----
    char* wsb = (char*)d_ws;
    ushort* nbf0    = (ushort*)wsb;   wsb += (size_t)N_NODES * DIM * 2;      // 25.6 MB
    int* head2      = (int*)wsb;      wsb += (size_t)2 * N_NODES * 4;        //  0.8 MB
    int2* entry2    = (int2*)wsb;     wsb += (size_t)2 * N_EDGES * 8;        //  8.0 MB
    ushort* wbf_ps  = (ushort*)wsb;   wsb += (size_t)DIM * DIM * 2;
    ushort* wbf_pn  = (ushort*)wsb;   wsb += (size_t)DIM * DIM * 2;
    ushort* wbf_bs  = (ushort*)wsb;   wsb += (size_t)DIM * DIM * 2;
    ushort* wbf_bn  = (ushort*)wsb;   wsb += (size_t)DIM * DIM * 2;
    float* dself_t  = (float*)wsb;    wsb += (size_t)N_NODES * 4;
    float* scross_t = (float*)wsb;    wsb += (size_t)N_NODES * 4;
    float* dself_u  = (float*)wsb;    wsb += (size_t)N_NODES * 4;
    float* scross_u = (float*)wsb;    wsb += (size_t)N_NODES * 4;
    float* smean_u  = (float*)wsb;    wsb += (size_t)N_NODES * 4;
    ushort* nbf1    = (ushort*)wsb;   wsb += (size_t)N_NODES * DIM * 2;      // 25.6 MB
    ushort* xbf_u   = (ushort*)wsb;   wsb += (size_t)N_NODES * DIM * 2;      // 25.6 MB
    ushort* xbf_t   = (ushort*)wsb;   wsb += (size_t)N_NODES * DIM * 2;      // 25.6 MB
    const bool use_bf = ((size_t)(wsb - (char*)d_ws) <= ws_size);

    int* head_posts = head2;
    int* head_pb    = head2 + N_NODES;
    int2* ent_posts = entry2;
    int2* ent_pb    = entry2 + N_EDGES;

    hipMemsetAsync(head2, 0xFF, (size_t)2 * N_NODES * sizeof(int), stream);

    if (!use_bf) {
        cvtw_kernel<<<dim3(16, 4), 256, 0, stream>>>(w1ps, w1pn, w1bs, w1bn,
                                                     wbf_ps, wbf_pn, wbf_bs, wbf_bn);
        build_lists2_kernel<<<dim3(GB_E, 2), 256, 0, stream>>>(
            src_posts, dst_posts, src_pb, dst_pb, head2, entry2);
        seg_mean_f32_list_kernel<<<(N_NODES * 32 + 255) / 256, 256, 0, stream>>>(
            x_user, head_posts, ent_posts, nbf0);
        gemm_mfma_f32_kernel<<<GB_G, 256, 0, stream>>>(x_tweet, nbf0, wbf_ps, wbf_pn,
                                                       b1ps, b1pn, w2ps, w2bn,
                                                       dself_t, scross_t);
        seg_mean_f32_list_kernel<<<(N_NODES * 32 + 255) / 256, 256, 0, stream>>>(
            x_tweet, head_pb, ent_pb, nbf0);
        gemm_mfma_f32_kernel<<<GB_G, 256, 0, stream>>>(x_user, nbf0, wbf_bs, wbf_bn,
                                                       b1bs, b1bn, w2bs, w2pn,
                                                       dself_u, scross_u);
        scalar_finalize_kernel<<<GB_N, 256, 0, stream>>>(dself_u, dself_t,
                                                         scross_u, scross_t,
                                                         head2, entry2,
                                                         b2bs, b2bn, b2ps, b2pn, out);
        return;
    }

    // -------- bf16 fast path --------
    // K1: pure-BW conversions (no atomics co-resident)
    cvt_fat_kernel<<<64 + 2 * GB_CVT, 256, 0, stream>>>(
        w1ps, w1pn, w1bs, w1bn, wbf_ps, wbf_pn, wbf_bs, wbf_bn,
        x_user, x_tweet, xbf_u, xbf_t);

    // K2: build rel0 alone (atomic-bound, machine otherwise idle)
    build1_kernel<<<GB_E, 256, 0, stream>>>(src_posts, dst_posts, head_posts, ent_posts);

    // K3: build rel1 (atomic) || seg0 (gather-latency) — complementary-ish pipes
    fatS_kernel<<<GB_E + GB_SEG, 256, 0, stream>>>(
        src_pb, dst_pb, head_pb, ent_pb, xbf_u, head_posts, ent_posts, nbf0);

    // K4: gemm rel0 (MFMA) || seg1 (gather)
    fatB_kernel<<<GB_G + GB_SEG, 256, 0, stream>>>(
        xbf_t, nbf0, wbf_ps, wbf_pn, b1ps, b1pn, w2ps, w2bn,
        dself_t, scross_t, head_pb, ent_pb, nbf1);

    // K5: gemm rel1 || user-side scalar traversal
    fatC_kernel<<<GB_G + GB_N, 256, 0, stream>>>(
        xbf_u, nbf1, wbf_bs, wbf_bn, b1bs, b1bn, w2bs, w2pn,
        dself_u, scross_u, scross_t, head_pb, ent_pb, smean_u);

    // K6: tweet-side traversal + output assembly
    tail_kernel<<<GB_N, 256, 0, stream>>>(dself_u, smean_u, dself_t, scross_u,
                                          head_posts, ent_posts,
                                          b2bs, b2bn, b2ps, b2pn, out);
}

// Round 9
// 200.034 us; speedup vs baseline: 1.1071x; 1.0921x over previous
//
#include <hip/hip_runtime.h>

#define N_NODES 100000
#define N_EDGES 500000
#define DIM 128
#define GB_E 1954      // ceil(E/256)
#define GB_EI 489      // ceil(E/1024) — 4 edges per thread (ILP build)
#define GB_N 391       // ceil(N/256)
#define GB_CVT 12500   // N*DIM/1024 per feature matrix
#define GB_G 782       // ceil(N/128) gemm tiles
#define GB_SEG 6250    // N*16/256 seg-mean blocks

typedef __attribute__((ext_vector_type(8))) short short8;   // 8 bf16 = 4 VGPRs
typedef __attribute__((ext_vector_type(4))) float f32x4;

__device__ __forceinline__ ushort f2bf(float f) {
    unsigned u = __float_as_uint(f);
    u += 0x7FFF + ((u >> 16) & 1);   // round-to-nearest-even
    return (ushort)(u >> 16);
}
__device__ __forceinline__ float bf2f(ushort s) {
    return __uint_as_float(((unsigned)s) << 16);
}

// ================= device bodies ====================================================

// 1-edge/thread build (fallback path)
__device__ __forceinline__ void build_body(const int* __restrict__ src,
                                           const int* __restrict__ dst,
                                           int* __restrict__ head,
                                           int2* __restrict__ entry, int bid) {
    int e = bid * 256 + threadIdx.x;
    if (e < N_EDGES) {
        int d = dst[e];
        int old = atomicExch(&head[d], e);
        entry[e] = make_int2(src[e], old);
    }
}

// 4-edge/thread ILP build: 4 independent atomicExch in flight per lane
__device__ __forceinline__ void build_body_ilp(const int* __restrict__ src,
                                               const int* __restrict__ dst,
                                               int* __restrict__ head,
                                               int2* __restrict__ entry, int bid) {
    int base = bid * 1024 + threadIdx.x;
    int e[4], d[4], s[4], old[4];
    bool ok[4];
#pragma unroll
    for (int k = 0; k < 4; ++k) {
        e[k] = base + k * 256;
        ok[k] = (e[k] < N_EDGES);
        d[k] = ok[k] ? dst[e[k]] : 0;
        s[k] = ok[k] ? src[e[k]] : 0;
    }
#pragma unroll
    for (int k = 0; k < 4; ++k)
        if (ok[k]) old[k] = atomicExch(&head[d[k]], e[k]);
#pragma unroll
    for (int k = 0; k < 4; ++k)
        if (ok[k]) entry[e[k]] = make_int2(s[k], old[k]);
}

__device__ __forceinline__ void cvt_body(const float* __restrict__ in,
                                         ushort* __restrict__ out, int bid) {
    int i = (bid * 256 + threadIdx.x) * 4;
    float4 v = *reinterpret_cast<const float4*>(&in[i]);
    ushort4 u = make_ushort4(f2bf(v.x), f2bf(v.y), f2bf(v.z), f2bf(v.w));
    *reinterpret_cast<ushort4*>(&out[i]) = u;
}

// bf16 seg-mean: 16 lanes/node, each lane owns 8 feats (16B loads)
__device__ __forceinline__ void seg_body(const ushort* __restrict__ x,
                                         const int* __restrict__ head,
                                         const int2* __restrict__ entry,
                                         ushort* __restrict__ outbf, int bid) {
    int idx = bid * 256 + threadIdx.x;
    int node = idx >> 4;
    if (node >= N_NODES) return;
    int f = (idx & 15) << 3;
    float acc[8];
#pragma unroll
    for (int j = 0; j < 8; ++j) acc[j] = 0.f;
    int cnt = 0;
    int e = head[node];
    while (e >= 0) {
        int2 nd = entry[e];   // dependent 8B load, broadcast within 16-lane group
        ++cnt;
        short8 v = *reinterpret_cast<const short8*>(&x[(size_t)nd.x * DIM + f]);
#pragma unroll
        for (int j = 0; j < 8; ++j) acc[j] += bf2f((ushort)v[j]);
        e = nd.y;
    }
    float r = 1.0f / fmaxf((float)cnt, 1.0f);
    union { ushort s[8]; uint4 v; } u;
#pragma unroll
    for (int j = 0; j < 8; ++j) u.s[j] = f2bf(acc[j] * r);
    *reinterpret_cast<uint4*>(&outbf[(size_t)node * DIM + f]) = u.v;
}

__device__ __forceinline__ float smean_body(const float* __restrict__ sval,
                                            const int* __restrict__ head,
                                            const int2* __restrict__ entry, int node) {
    float a = 0.f;
    int cnt = 0;
    int e = head[node];
    while (e >= 0) {
        int2 nd = entry[e];
        ++cnt;
        a += sval[nd.x];
        e = nd.y;
    }
    return a / fmaxf((float)cnt, 1.0f);
}

// fused layer-1 MFMA GEMM + layer-2 dots. h = relu(Xs@Ws.T+bs + Nm@Wn.T+bn);
// dself=h·w2a, dcross=h·w2b. 128x128 tile, 4 waves, K=256, BK=64, XOR-swizzled LDS.
__device__ __forceinline__ void gemm_body(
    const ushort* __restrict__ Xsbf, const ushort* __restrict__ Nm,
    const ushort* __restrict__ Wsbf, const ushort* __restrict__ Wnbf,
    const float* __restrict__ bs, const float* __restrict__ bn,
    const float* __restrict__ w2a, const float* __restrict__ w2b,
    float* __restrict__ dself, float* __restrict__ dcross, int blk) {
    __shared__ ushort sA[128 * 64];
    __shared__ ushort sB[128 * 64];
    __shared__ float pS[2][2][128];

    const int tid = threadIdx.x;
    const int lane = tid & 63;
    const int wid = tid >> 6;
    const int wr = wid >> 1, wc = wid & 1;
    const int lr = lane & 15, lg = lane >> 4;
    const int row0 = blk * 128;

    f32x4 acc[4][4];
#pragma unroll
    for (int i = 0; i < 4; ++i)
#pragma unroll
        for (int j = 0; j < 4; ++j) acc[i][j] = (f32x4){0.f, 0.f, 0.f, 0.f};

    const int r = tid >> 1;
    const int hh = tid & 1;
    const int grow = row0 + r;
    const int swzr = (r & 7) << 4;

    for (int kb = 0; kb < 256; kb += 64) {
        const int kg = kb & 127;
        const bool self = (kb < 128);
        __syncthreads();
        {
            const uint4* g = reinterpret_cast<const uint4*>(self ? Xsbf : Nm);
#pragma unroll
            for (int q = 0; q < 4; ++q) {
                uint4 v = make_uint4(0, 0, 0, 0);
                if (grow < N_NODES)
                    v = g[((size_t)grow * DIM + kg + hh * 32 + q * 8) >> 3];
                int byte = (hh * 64 + q * 16) ^ swzr;
                *reinterpret_cast<uint4*>(&sA[r * 64 + (byte >> 1)]) = v;
            }
        }
        {
            const uint4* g = reinterpret_cast<const uint4*>(self ? Wsbf : Wnbf);
#pragma unroll
            for (int q = 0; q < 4; ++q) {
                uint4 v = g[(r * DIM + kg + hh * 32 + q * 8) >> 3];
                int byte = (hh * 64 + q * 16) ^ swzr;
                *reinterpret_cast<uint4*>(&sB[r * 64 + (byte >> 1)]) = v;
            }
        }
        __syncthreads();
#pragma unroll
        for (int ks = 0; ks < 2; ++ks) {
            short8 a[4], b[4];
#pragma unroll
            for (int fm = 0; fm < 4; ++fm) {
                int rr = wr * 64 + fm * 16 + lr;
                int byte = (ks * 64 + lg * 16) ^ ((rr & 7) << 4);
                a[fm] = *reinterpret_cast<const short8*>(&sA[rr * 64 + (byte >> 1)]);
            }
#pragma unroll
            for (int fn = 0; fn < 4; ++fn) {
                int cc = wc * 64 + fn * 16 + lr;
                int byte = (ks * 64 + lg * 16) ^ ((cc & 7) << 4);
                b[fn] = *reinterpret_cast<const short8*>(&sB[cc * 64 + (byte >> 1)]);
            }
#pragma unroll
            for (int fm = 0; fm < 4; ++fm)
#pragma unroll
                for (int fn = 0; fn < 4; ++fn)
                    acc[fm][fn] = __builtin_amdgcn_mfma_f32_16x16x32_bf16(
                        a[fm], b[fn], acc[fm][fn], 0, 0, 0);
        }
    }

    float bias[4], wa[4], wb[4];
#pragma unroll
    for (int fn = 0; fn < 4; ++fn) {
        int c = wc * 64 + fn * 16 + lr;
        bias[fn] = bs[c] + bn[c];
        wa[fn] = w2a[c];
        wb[fn] = w2b[c];
    }
#pragma unroll
    for (int fm = 0; fm < 4; ++fm) {
#pragma unroll
        for (int reg = 0; reg < 4; ++reg) {
            float pa = 0.f, pb = 0.f;
#pragma unroll
            for (int fn = 0; fn < 4; ++fn) {
                float h = fmaxf(acc[fm][fn][reg] + bias[fn], 0.f);
                pa = fmaf(h, wa[fn], pa);
                pb = fmaf(h, wb[fn], pb);
            }
#pragma unroll
            for (int m = 1; m < 16; m <<= 1) {
                pa += __shfl_xor(pa, m);
                pb += __shfl_xor(pb, m);
            }
            if (lr == 0) {
                int rloc = wr * 64 + fm * 16 + lg * 4 + reg;   // C/D row=(lane>>4)*4+reg
                pS[wc][0][rloc] = pa;
                pS[wc][1][rloc] = pb;
            }
        }
    }
    __syncthreads();
    if (tid < 128) {
        int go = row0 + tid;
        if (go < N_NODES) {
            dself[go] = pS[0][0][tid] + pS[1][0][tid];
            dcross[go] = pS[0][1][tid] + pS[1][1][tid];
        }
    }
}

// ================= kernels ==========================================================

// cvt-fat: weight cvt (64 blocks) + both feature cvts (pure BW, no atomics)
__global__ __launch_bounds__(256) void cvt_fat_kernel(
    const float* __restrict__ w0, const float* __restrict__ w1,
    const float* __restrict__ w2, const float* __restrict__ w3,
    ushort* __restrict__ o0, ushort* __restrict__ o1,
    ushort* __restrict__ o2, ushort* __restrict__ o3,
    const float* __restrict__ xu, const float* __restrict__ xt,
    ushort* __restrict__ xbf_u, ushort* __restrict__ xbf_t) {
    int bid = blockIdx.x;
    if (bid < 64) {
        int a = bid >> 4;
        const float* in = (a == 0) ? w0 : (a == 1) ? w1 : (a == 2) ? w2 : w3;
        ushort* out = (a == 0) ? o0 : (a == 1) ? o1 : (a == 2) ? o2 : o3;
        cvt_body(in, out, bid & 15);
    } else {
        int b = bid - 64;
        int which = (b >= GB_CVT);
        cvt_body(which ? xt : xu, which ? xbf_t : xbf_u, b - which * GB_CVT);
    }
}

// build one relation, 4-edge ILP (standalone, atomic-bound)
__global__ __launch_bounds__(256) void build1_ilp_kernel(
    const int* __restrict__ src, const int* __restrict__ dst,
    int* __restrict__ head, int2* __restrict__ entry) {
    build_body_ilp(src, dst, head, entry, blockIdx.x);
}

// fatS: build rel1 ILP (atomic) || seg-mean rel0 (gather-latency). No LDS anywhere.
__global__ __launch_bounds__(256) void fatS_kernel(
    const int* __restrict__ s1, const int* __restrict__ d1,
    int* __restrict__ head_pb, int2* __restrict__ ent_pb,
    const ushort* __restrict__ xbf_u, const int* __restrict__ head_posts,
    const int2* __restrict__ ent_posts, ushort* __restrict__ nbf0) {
    int bid = blockIdx.x;
    if (bid < GB_EI)
        build_body_ilp(s1, d1, head_pb, ent_pb, bid);
    else
        seg_body(xbf_u, head_posts, ent_posts, nbf0, bid - GB_EI);
}

// standalone bf16 seg-mean
__global__ __launch_bounds__(256) void seg_only_kernel(
    const ushort* __restrict__ x, const int* __restrict__ head,
    const int2* __restrict__ entry, ushort* __restrict__ outbf) {
    seg_body(x, head, entry, outbf, blockIdx.x);
}

// standalone gemm
__global__ __launch_bounds__(256) void gemm_only_kernel(
    const ushort* __restrict__ Xsbf, const ushort* __restrict__ Nm,
    const ushort* __restrict__ Wsbf, const ushort* __restrict__ Wnbf,
    const float* __restrict__ bs, const float* __restrict__ bn,
    const float* __restrict__ w2a, const float* __restrict__ w2b,
    float* __restrict__ dself, float* __restrict__ dcross) {
    gemm_body(Xsbf, Nm, Wsbf, Wnbf, bs, bn, w2a, w2b, dself, dcross, blockIdx.x);
}

// fatC: gemm rel1 || user-side scalar traversal (reads only earlier outputs)
__global__ __launch_bounds__(256) void fatC_kernel(
    const ushort* __restrict__ xbf_u, const ushort* __restrict__ nbf1,
    const ushort* __restrict__ wbf_bs, const ushort* __restrict__ wbf_bn,
    const float* __restrict__ b1bs, const float* __restrict__ b1bn,
    const float* __restrict__ w2bs, const float* __restrict__ w2pn,
    float* __restrict__ dself_u, float* __restrict__ scross_u,
    const float* __restrict__ scross_t,
    const int* __restrict__ head_pb, const int2* __restrict__ ent_pb,
    float* __restrict__ smean_u) {
    int bid = blockIdx.x;
    if (bid < GB_G) {
        gemm_body(xbf_u, nbf1, wbf_bs, wbf_bn, b1bs, b1bn, w2bs, w2pn,
                  dself_u, scross_u, bid);
    } else {
        int i = (bid - GB_G) * 256 + threadIdx.x;
        if (i < N_NODES) smean_u[i] = smean_body(scross_t, head_pb, ent_pb, i);
    }
}

// tail: tweet-side traversal (needs gemm1's scross_u) + assemble both outputs
__global__ __launch_bounds__(256) void tail_kernel(
    const float* __restrict__ dself_u, const float* __restrict__ smean_u,
    const float* __restrict__ dself_t, const float* __restrict__ scross_u,
    const int* __restrict__ head_posts, const int2* __restrict__ ent_posts,
    const float* __restrict__ b2bs, const float* __restrict__ b2bn,
    const float* __restrict__ b2ps, const float* __restrict__ b2pn,
    float* __restrict__ out) {
    int i = blockIdx.x * 256 + threadIdx.x;
    if (i >= N_NODES) return;
    out[N_NODES + i] = dself_t[i] + smean_body(scross_u, head_posts, ent_posts, i)
                       + b2ps[0] + b2pn[0];
    out[i] = dself_u[i] + smean_u[i] + b2bs[0] + b2bn[0];
}

// -------- f32 fallback kernels (small-ws safety) --------

__global__ __launch_bounds__(256) void cvtw_kernel(
    const float* __restrict__ w0, const float* __restrict__ w1,
    const float* __restrict__ w2, const float* __restrict__ w3,
    ushort* __restrict__ o0, ushort* __restrict__ o1,
    ushort* __restrict__ o2, ushort* __restrict__ o3) {
    int a = blockIdx.y;
    const float* in = (a == 0) ? w0 : (a == 1) ? w1 : (a == 2) ? w2 : w3;
    ushort* out = (a == 0) ? o0 : (a == 1) ? o1 : (a == 2) ? o2 : o3;
    cvt_body(in, out, blockIdx.x);
}

__global__ __launch_bounds__(256) void build_lists2_kernel(
    const int* __restrict__ s0, const int* __restrict__ d0,
    const int* __restrict__ s1, const int* __restrict__ d1,
    int* __restrict__ head2, int2* __restrict__ entry2) {
    const int rel = blockIdx.y;
    build_body(rel ? s1 : s0, rel ? d1 : d0, head2 + (size_t)rel * N_NODES,
               entry2 + (size_t)rel * N_EDGES, blockIdx.x);
}

__global__ __launch_bounds__(256) void seg_mean_f32_list_kernel(
    const float* __restrict__ x, const int* __restrict__ head,
    const int2* __restrict__ entry, ushort* __restrict__ outbf) {
    int idx = blockIdx.x * 256 + threadIdx.x;
    int node = idx >> 5;
    if (node >= N_NODES) return;
    int f = (idx & 31) << 2;
    float4 acc = make_float4(0.f, 0.f, 0.f, 0.f);
    int cnt = 0;
    int e = head[node];
    while (e >= 0) {
        int2 nd = entry[e];
        ++cnt;
        float4 v = *reinterpret_cast<const float4*>(&x[(size_t)nd.x * DIM + f]);
        acc.x += v.x; acc.y += v.y; acc.z += v.z; acc.w += v.w;
        e = nd.y;
    }
    float r = 1.0f / fmaxf((float)cnt, 1.0f);
    ushort4 u = make_ushort4(f2bf(acc.x * r), f2bf(acc.y * r),
                             f2bf(acc.z * r), f2bf(acc.w * r));
    *reinterpret_cast<ushort4*>(&outbf[node * DIM + f]) = u;
}

__global__ __launch_bounds__(256) void gemm_mfma_f32_kernel(
    const float* __restrict__ Xs, const ushort* __restrict__ Nm,
    const ushort* __restrict__ Wsbf, const ushort* __restrict__ Wnbf,
    const float* __restrict__ bs, const float* __restrict__ bn,
    const float* __restrict__ w2a, const float* __restrict__ w2b,
    float* __restrict__ dself, float* __restrict__ dcross) {
    __shared__ ushort sA[128 * 64];
    __shared__ ushort sB[128 * 64];
    __shared__ float pS[2][2][128];

    const int tid = threadIdx.x;
    const int lane = tid & 63;
    const int wid = tid >> 6;
    const int wr = wid >> 1, wc = wid & 1;
    const int lr = lane & 15, lg = lane >> 4;
    const int row0 = blockIdx.x * 128;

    f32x4 acc[4][4];
#pragma unroll
    for (int i = 0; i < 4; ++i)
#pragma unroll
        for (int j = 0; j < 4; ++j) acc[i][j] = (f32x4){0.f, 0.f, 0.f, 0.f};

    const int r = tid >> 1;
    const int hh = tid & 1;
    const int grow = row0 + r;
    const int swzr = (r & 7) << 4;

    for (int kb = 0; kb < 256; kb += 64) {
        const int kg = kb & 127;
        const bool self = (kb < 128);
        __syncthreads();
        if (self) {
            const float4* g = reinterpret_cast<const float4*>(Xs);
#pragma unroll
            for (int q = 0; q < 4; ++q) {
                float4 v0 = make_float4(0.f, 0.f, 0.f, 0.f), v1 = v0;
                if (grow < N_NODES) {
                    size_t bi = ((size_t)grow * DIM + kg + hh * 32 + q * 8) >> 2;
                    v0 = g[bi];
                    v1 = g[bi + 1];
                }
                union { ushort s[8]; uint4 v; } u;
                u.s[0] = f2bf(v0.x); u.s[1] = f2bf(v0.y);
                u.s[2] = f2bf(v0.z); u.s[3] = f2bf(v0.w);
                u.s[4] = f2bf(v1.x); u.s[5] = f2bf(v1.y);
                u.s[6] = f2bf(v1.z); u.s[7] = f2bf(v1.w);
                int byte = (hh * 64 + q * 16) ^ swzr;
                *reinterpret_cast<uint4*>(&sA[r * 64 + (byte >> 1)]) = u.v;
            }
        } else {
            const uint4* g = reinterpret_cast<const uint4*>(Nm);
#pragma unroll
            for (int q = 0; q < 4; ++q) {
                uint4 v = make_uint4(0, 0, 0, 0);
                if (grow < N_NODES)
                    v = g[((size_t)grow * DIM + kg + hh * 32 + q * 8) >> 3];
                int byte = (hh * 64 + q * 16) ^ swzr;
                *reinterpret_cast<uint4*>(&sA[r * 64 + (byte >> 1)]) = v;
            }
        }
        {
            const uint4* g = reinterpret_cast<const uint4*>(self ? Wsbf : Wnbf);
#pragma unroll
            for (int q = 0; q < 4; ++q) {
                uint4 v = g[(r * DIM + kg + hh * 32 + q * 8) >> 3];
                int byte = (hh * 64 + q * 16) ^ swzr;
                *reinterpret_cast<uint4*>(&sB[r * 64 + (byte >> 1)]) = v;
            }
        }
        __syncthreads();
#pragma unroll
        for (int ks = 0; ks < 2; ++ks) {
            short8 a[4], b[4];
#pragma unroll
            for (int fm = 0; fm < 4; ++fm) {
                int rr = wr * 64 + fm * 16 + lr;
                int byte = (ks * 64 + lg * 16) ^ ((rr & 7) << 4);
                a[fm] = *reinterpret_cast<const short8*>(&sA[rr * 64 + (byte >> 1)]);
            }
#pragma unroll
            for (int fn = 0; fn < 4; ++fn) {
                int cc = wc * 64 + fn * 16 + lr;
                int byte = (ks * 64 + lg * 16) ^ ((cc & 7) << 4);
                b[fn] = *reinterpret_cast<const short8*>(&sB[cc * 64 + (byte >> 1)]);
            }
#pragma unroll
            for (int fm = 0; fm < 4; ++fm)
#pragma unroll
                for (int fn = 0; fn < 4; ++fn)
                    acc[fm][fn] = __builtin_amdgcn_mfma_f32_16x16x32_bf16(
                        a[fm], b[fn], acc[fm][fn], 0, 0, 0);
        }
    }

    float bias[4], wa[4], wb[4];
#pragma unroll
    for (int fn = 0; fn < 4; ++fn) {
        int c = wc * 64 + fn * 16 + lr;
        bias[fn] = bs[c] + bn[c];
        wa[fn] = w2a[c];
        wb[fn] = w2b[c];
    }
#pragma unroll
    for (int fm = 0; fm < 4; ++fm) {
#pragma unroll
        for (int reg = 0; reg < 4; ++reg) {
            float pa = 0.f, pb = 0.f;
#pragma unroll
            for (int fn = 0; fn < 4; ++fn) {
                float h = fmaxf(acc[fm][fn][reg] + bias[fn], 0.f);
                pa = fmaf(h, wa[fn], pa);
                pb = fmaf(h, wb[fn], pb);
            }
#pragma unroll
            for (int m = 1; m < 16; m <<= 1) {
                pa += __shfl_xor(pa, m);
                pb += __shfl_xor(pb, m);
            }
            if (lr == 0) {
                int rloc = wr * 64 + fm * 16 + lg * 4 + reg;
                pS[wc][0][rloc] = pa;
                pS[wc][1][rloc] = pb;
            }
        }
    }
    __syncthreads();
    if (tid < 128) {
        int go = row0 + tid;
        if (go < N_NODES) {
            dself[go] = pS[0][0][tid] + pS[1][0][tid];
            dcross[go] = pS[0][1][tid] + pS[1][1][tid];
        }
    }
}

__global__ __launch_bounds__(256) void scalar_finalize_kernel(
    const float* __restrict__ dself_u, const float* __restrict__ dself_t,
    const float* __restrict__ scross_u, const float* __restrict__ scross_t,
    const int* __restrict__ head2, const int2* __restrict__ entry2,
    const float* __restrict__ b2bs, const float* __restrict__ b2bn,
    const float* __restrict__ b2ps, const float* __restrict__ b2pn,
    float* __restrict__ out) {
    int i = blockIdx.x * 256 + threadIdx.x;
    if (i >= N_NODES) return;
    out[N_NODES + i] = dself_t[i] + smean_body(scross_u, head2, entry2, i)
                       + b2ps[0] + b2pn[0];
    out[i] = dself_u[i] + smean_body(scross_t, head2 + N_NODES, entry2 + N_EDGES, i)
             + b2bs[0] + b2bn[0];
}

// ===================================================================================

extern "C" void kernel_launch(void* const* d_in, const int* in_sizes, int n_in,
                              void* d_out, int out_size, void* d_ws, size_t ws_size,
                              hipStream_t stream) {
    const float* x_user  = (const float*)d_in[0];
    const float* x_tweet = (const float*)d_in[1];
    const float* w1ps = (const float*)d_in[2];  const float* b1ps = (const float*)d_in[3];
    const float* w1pn = (const float*)d_in[4];  const float* b1pn = (const float*)d_in[5];
    const float* w1bs = (const float*)d_in[6];  const float* b1bs = (const float*)d_in[7];
    const float* w1bn = (const float*)d_in[8];  const float* b1bn = (const float*)d_in[9];
    const float* w2ps = (const float*)d_in[10]; const float* b2ps = (const float*)d_in[11];
    const float* w2pn = (const float*)d_in[12]; const float* b2pn = (const float*)d_in[13];
    const float* w2bs = (const float*)d_in[14]; const float* b2bs = (const float*)d_in[15];
    const float* w2bn = (const float*)d_in[16]; const float* b2bn = (const float*)d_in[17];
    const int* src_posts = (const int*)d_in[18];
    const int* dst_posts = (const int*)d_in[19];
    const int* src_pb    = (const int*)d_in[20];
    const int* dst_pb    = (const int*)d_in[21];
    float* out = (float*)d_out;

    // ---- workspace layout (16B aligned regions) ----
    char* wsb = (char*)d_ws;
    ushort* nbf0    = (ushort*)wsb;   wsb += (size_t)N_NODES * DIM * 2;      // 25.6 MB
    int* head2      = (int*)wsb;      wsb += (size_t)2 * N_NODES * 4;        //  0.8 MB
    int2* entry2    = (int2*)wsb;     wsb += (size_t)2 * N_EDGES * 8;        //  8.0 MB
    ushort* wbf_ps  = (ushort*)wsb;   wsb += (size_t)DIM * DIM * 2;
    ushort* wbf_pn  = (ushort*)wsb;   wsb += (size_t)DIM * DIM * 2;
    ushort* wbf_bs  = (ushort*)wsb;   wsb += (size_t)DIM * DIM * 2;
    ushort* wbf_bn  = (ushort*)wsb;   wsb += (size_t)DIM * DIM * 2;
    float* dself_t  = (float*)wsb;    wsb += (size_t)N_NODES * 4;
    float* scross_t = (float*)wsb;    wsb += (size_t)N_NODES * 4;
    float* dself_u  = (float*)wsb;    wsb += (size_t)N_NODES * 4;
    float* scross_u = (float*)wsb;    wsb += (size_t)N_NODES * 4;
    float* smean_u  = (float*)wsb;    wsb += (size_t)N_NODES * 4;
    ushort* nbf1    = (ushort*)wsb;   wsb += (size_t)N_NODES * DIM * 2;      // 25.6 MB
    ushort* xbf_u   = (ushort*)wsb;   wsb += (size_t)N_NODES * DIM * 2;      // 25.6 MB
    ushort* xbf_t   = (ushort*)wsb;   wsb += (size_t)N_NODES * DIM * 2;      // 25.6 MB
    const bool use_bf = ((size_t)(wsb - (char*)d_ws) <= ws_size);

    int* head_posts = head2;
    int* head_pb    = head2 + N_NODES;
    int2* ent_posts = entry2;
    int2* ent_pb    = entry2 + N_EDGES;

    hipMemsetAsync(head2, 0xFF, (size_t)2 * N_NODES * sizeof(int), stream);

    if (!use_bf) {
        cvtw_kernel<<<dim3(16, 4), 256, 0, stream>>>(w1ps, w1pn, w1bs, w1bn,
                                                     wbf_ps, wbf_pn, wbf_bs, wbf_bn);
        build_lists2_kernel<<<dim3(GB_E, 2), 256, 0, stream>>>(
            src_posts, dst_posts, src_pb, dst_pb, head2, entry2);
        seg_mean_f32_list_kernel<<<(N_NODES * 32 + 255) / 256, 256, 0, stream>>>(
            x_user, head_posts, ent_posts, nbf0);
        gemm_mfma_f32_kernel<<<GB_G, 256, 0, stream>>>(x_tweet, nbf0, wbf_ps, wbf_pn,
                                                       b1ps, b1pn, w2ps, w2bn,
                                                       dself_t, scross_t);
        seg_mean_f32_list_kernel<<<(N_NODES * 32 + 255) / 256, 256, 0, stream>>>(
            x_tweet, head_pb, ent_pb, nbf0);
        gemm_mfma_f32_kernel<<<GB_G, 256, 0, stream>>>(x_user, nbf0, wbf_bs, wbf_bn,
                                                       b1bs, b1bn, w2bs, w2pn,
                                                       dself_u, scross_u);
        scalar_finalize_kernel<<<GB_N, 256, 0, stream>>>(dself_u, dself_t,
                                                         scross_u, scross_t,
                                                         head2, entry2,
                                                         b2bs, b2bn, b2ps, b2pn, out);
        return;
    }

    // -------- bf16 fast path --------
    // K1: pure-BW conversions (no atomics co-resident)
    cvt_fat_kernel<<<64 + 2 * GB_CVT, 256, 0, stream>>>(
        w1ps, w1pn, w1bs, w1bn, wbf_ps, wbf_pn, wbf_bs, wbf_bn,
        x_user, x_tweet, xbf_u, xbf_t);

    // K2: build rel0 alone, 4-edge ILP (atomic-bound)
    build1_ilp_kernel<<<GB_EI, 256, 0, stream>>>(src_posts, dst_posts,
                                                 head_posts, ent_posts);

    // K3: build rel1 ILP (atomic) || seg0 (gather-latency) — no LDS in either
    fatS_kernel<<<GB_EI + GB_SEG, 256, 0, stream>>>(
        src_pb, dst_pb, head_pb, ent_pb, xbf_u, head_posts, ent_posts, nbf0);

    // K4: gemm rel0 (standalone, full occupancy for its LDS footprint)
    gemm_only_kernel<<<GB_G, 256, 0, stream>>>(xbf_t, nbf0, wbf_ps, wbf_pn,
                                               b1ps, b1pn, w2ps, w2bn,
                                               dself_t, scross_t);

    // K5: seg1 (standalone, full occupancy gather)
    seg_only_kernel<<<GB_SEG, 256, 0, stream>>>(xbf_t, head_pb, ent_pb, nbf1);

    // K6: gemm rel1 || user-side scalar traversal
    fatC_kernel<<<GB_G + GB_N, 256, 0, stream>>>(
        xbf_u, nbf1, wbf_bs, wbf_bn, b1bs, b1bn, w2bs, w2pn,
        dself_u, scross_u, scross_t, head_pb, ent_pb, smean_u);

    // K7: tweet-side traversal + output assembly
    tail_kernel<<<GB_N, 256, 0, stream>>>(dself_u, smean_u, dself_t, scross_u,
                                          head_posts, ent_posts,
                                          b2bs, b2bn, b2ps, b2pn, out);
}

// Round 10
// 197.486 us; speedup vs baseline: 1.1213x; 1.0129x over previous
//
#include <hip/hip_runtime.h>

#define N_NODES 100000
#define N_EDGES 500000
#define DIM 128
#define GB_E 1954      // ceil(E/256)
#define GB_EI 489      // ceil(E/1024) — 4 edges per thread (ILP build)
#define GB_N 391       // ceil(N/256)
#define GB_CVT 12500   // N*DIM/1024 per feature matrix
#define GB_G 782       // ceil(N/128) gemm tiles
#define GB_SEG 6250    // N*16/256 seg-mean blocks

typedef __attribute__((ext_vector_type(8))) short short8;   // 8 bf16 = 4 VGPRs
typedef __attribute__((ext_vector_type(4))) float f32x4;

__device__ __forceinline__ ushort f2bf(float f) {
    unsigned u = __float_as_uint(f);
    u += 0x7FFF + ((u >> 16) & 1);   // round-to-nearest-even
    return (ushort)(u >> 16);
}
__device__ __forceinline__ float bf2f(ushort s) {
    return __uint_as_float(((unsigned)s) << 16);
}

// ================= device bodies ====================================================

// 1-edge/thread build (fallback path)
__device__ __forceinline__ void build_body(const int* __restrict__ src,
                                           const int* __restrict__ dst,
                                           int* __restrict__ head,
                                           int2* __restrict__ entry, int bid) {
    int e = bid * 256 + threadIdx.x;
    if (e < N_EDGES) {
        int d = dst[e];
        int old = atomicExch(&head[d], e);
        entry[e] = make_int2(src[e], old);
    }
}

// 4-edge/thread ILP build: 4 independent atomicExch in flight per lane.
// ILP (not TLP) keeps the atomic pipe fed even at low block co-residency,
// which lets this branch ride inside an LDS-heavy fat dispatch.
__device__ __forceinline__ void build_body_ilp(const int* __restrict__ src,
                                               const int* __restrict__ dst,
                                               int* __restrict__ head,
                                               int2* __restrict__ entry, int bid) {
    int base = bid * 1024 + threadIdx.x;
    int e[4], d[4], s[4], old[4];
    bool ok[4];
#pragma unroll
    for (int k = 0; k < 4; ++k) {
        e[k] = base + k * 256;
        ok[k] = (e[k] < N_EDGES);
        d[k] = ok[k] ? dst[e[k]] : 0;
        s[k] = ok[k] ? src[e[k]] : 0;
    }
#pragma unroll
    for (int k = 0; k < 4; ++k)
        if (ok[k]) old[k] = atomicExch(&head[d[k]], e[k]);
#pragma unroll
    for (int k = 0; k < 4; ++k)
        if (ok[k]) entry[e[k]] = make_int2(s[k], old[k]);
}

__device__ __forceinline__ void cvt_body(const float* __restrict__ in,
                                         ushort* __restrict__ out, int bid) {
    int i = (bid * 256 + threadIdx.x) * 4;
    float4 v = *reinterpret_cast<const float4*>(&in[i]);
    ushort4 u = make_ushort4(f2bf(v.x), f2bf(v.y), f2bf(v.z), f2bf(v.w));
    *reinterpret_cast<ushort4*>(&out[i]) = u;
}

// bf16 seg-mean: 16 lanes/node, each lane owns 8 feats (16B loads)
__device__ __forceinline__ void seg_body(const ushort* __restrict__ x,
                                         const int* __restrict__ head,
                                         const int2* __restrict__ entry,
                                         ushort* __restrict__ outbf, int bid) {
    int idx = bid * 256 + threadIdx.x;
    int node = idx >> 4;
    if (node >= N_NODES) return;
    int f = (idx & 15) << 3;
    float acc[8];
#pragma unroll
    for (int j = 0; j < 8; ++j) acc[j] = 0.f;
    int cnt = 0;
    int e = head[node];
    while (e >= 0) {
        int2 nd = entry[e];   // dependent 8B load, broadcast within 16-lane group
        ++cnt;
        short8 v = *reinterpret_cast<const short8*>(&x[(size_t)nd.x * DIM + f]);
#pragma unroll
        for (int j = 0; j < 8; ++j) acc[j] += bf2f((ushort)v[j]);
        e = nd.y;
    }
    float r = 1.0f / fmaxf((float)cnt, 1.0f);
    union { ushort s[8]; uint4 v; } u;
#pragma unroll
    for (int j = 0; j < 8; ++j) u.s[j] = f2bf(acc[j] * r);
    *reinterpret_cast<uint4*>(&outbf[(size_t)node * DIM + f]) = u.v;
}

__device__ __forceinline__ float smean_body(const float* __restrict__ sval,
                                            const int* __restrict__ head,
                                            const int2* __restrict__ entry, int node) {
    float a = 0.f;
    int cnt = 0;
    int e = head[node];
    while (e >= 0) {
        int2 nd = entry[e];
        ++cnt;
        a += sval[nd.x];
        e = nd.y;
    }
    return a / fmaxf((float)cnt, 1.0f);
}

// fused layer-1 MFMA GEMM + layer-2 dots. h = relu(Xs@Ws.T+bs + Nm@Wn.T+bn);
// dself=h·w2a, dcross=h·w2b. 128x128 tile, 4 waves, K=256, BK=64, XOR-swizzled LDS.
__device__ __forceinline__ void gemm_body(
    const ushort* __restrict__ Xsbf, const ushort* __restrict__ Nm,
    const ushort* __restrict__ Wsbf, const ushort* __restrict__ Wnbf,
    const float* __restrict__ bs, const float* __restrict__ bn,
    const float* __restrict__ w2a, const float* __restrict__ w2b,
    float* __restrict__ dself, float* __restrict__ dcross, int blk) {
    __shared__ ushort sA[128 * 64];
    __shared__ ushort sB[128 * 64];
    __shared__ float pS[2][2][128];

    const int tid = threadIdx.x;
    const int lane = tid & 63;
    const int wid = tid >> 6;
    const int wr = wid >> 1, wc = wid & 1;
    const int lr = lane & 15, lg = lane >> 4;
    const int row0 = blk * 128;

    f32x4 acc[4][4];
#pragma unroll
    for (int i = 0; i < 4; ++i)
#pragma unroll
        for (int j = 0; j < 4; ++j) acc[i][j] = (f32x4){0.f, 0.f, 0.f, 0.f};

    const int r = tid >> 1;
    const int hh = tid & 1;
    const int grow = row0 + r;
    const int swzr = (r & 7) << 4;

    for (int kb = 0; kb < 256; kb += 64) {
        const int kg = kb & 127;
        const bool self = (kb < 128);
        __syncthreads();
        {
            const uint4* g = reinterpret_cast<const uint4*>(self ? Xsbf : Nm);
#pragma unroll
            for (int q = 0; q < 4; ++q) {
                uint4 v = make_uint4(0, 0, 0, 0);
                if (grow < N_NODES)
                    v = g[((size_t)grow * DIM + kg + hh * 32 + q * 8) >> 3];
                int byte = (hh * 64 + q * 16) ^ swzr;
                *reinterpret_cast<uint4*>(&sA[r * 64 + (byte >> 1)]) = v;
            }
        }
        {
            const uint4* g = reinterpret_cast<const uint4*>(self ? Wsbf : Wnbf);
#pragma unroll
            for (int q = 0; q < 4; ++q) {
                uint4 v = g[(r * DIM + kg + hh * 32 + q * 8) >> 3];
                int byte = (hh * 64 + q * 16) ^ swzr;
                *reinterpret_cast<uint4*>(&sB[r * 64 + (byte >> 1)]) = v;
            }
        }
        __syncthreads();
#pragma unroll
        for (int ks = 0; ks < 2; ++ks) {
            short8 a[4], b[4];
#pragma unroll
            for (int fm = 0; fm < 4; ++fm) {
                int rr = wr * 64 + fm * 16 + lr;
                int byte = (ks * 64 + lg * 16) ^ ((rr & 7) << 4);
                a[fm] = *reinterpret_cast<const short8*>(&sA[rr * 64 + (byte >> 1)]);
            }
#pragma unroll
            for (int fn = 0; fn < 4; ++fn) {
                int cc = wc * 64 + fn * 16 + lr;
                int byte = (ks * 64 + lg * 16) ^ ((cc & 7) << 4);
                b[fn] = *reinterpret_cast<const short8*>(&sB[cc * 64 + (byte >> 1)]);
            }
#pragma unroll
            for (int fm = 0; fm < 4; ++fm)
#pragma unroll
                for (int fn = 0; fn < 4; ++fn)
                    acc[fm][fn] = __builtin_amdgcn_mfma_f32_16x16x32_bf16(
                        a[fm], b[fn], acc[fm][fn], 0, 0, 0);
        }
    }

    float bias[4], wa[4], wb[4];
#pragma unroll
    for (int fn = 0; fn < 4; ++fn) {
        int c = wc * 64 + fn * 16 + lr;
        bias[fn] = bs[c] + bn[c];
        wa[fn] = w2a[c];
        wb[fn] = w2b[c];
    }
#pragma unroll
    for (int fm = 0; fm < 4; ++fm) {
#pragma unroll
        for (int reg = 0; reg < 4; ++reg) {
            float pa = 0.f, pb = 0.f;
#pragma unroll
            for (int fn = 0; fn < 4; ++fn) {
                float h = fmaxf(acc[fm][fn][reg] + bias[fn], 0.f);
                pa = fmaf(h, wa[fn], pa);
                pb = fmaf(h, wb[fn], pb);
            }
#pragma unroll
            for (int m = 1; m < 16; m <<= 1) {
                pa += __shfl_xor(pa, m);
                pb += __shfl_xor(pb, m);
            }
            if (lr == 0) {
                int rloc = wr * 64 + fm * 16 + lg * 4 + reg;   // C/D row=(lane>>4)*4+reg
                pS[wc][0][rloc] = pa;
                pS[wc][1][rloc] = pb;
            }
        }
    }
    __syncthreads();
    if (tid < 128) {
        int go = row0 + tid;
        if (go < N_NODES) {
            dself[go] = pS[0][0][tid] + pS[1][0][tid];
            dcross[go] = pS[0][1][tid] + pS[1][1][tid];
        }
    }
}

// ================= kernels ==========================================================

// cvt-fat: weight cvt (64 blocks) + both feature cvts (pure BW, no atomics)
__global__ __launch_bounds__(256) void cvt_fat_kernel(
    const float* __restrict__ w0, const float* __restrict__ w1,
    const float* __restrict__ w2, const float* __restrict__ w3,
    ushort* __restrict__ o0, ushort* __restrict__ o1,
    ushort* __restrict__ o2, ushort* __restrict__ o3,
    const float* __restrict__ xu, const float* __restrict__ xt,
    ushort* __restrict__ xbf_u, ushort* __restrict__ xbf_t) {
    int bid = blockIdx.x;
    if (bid < 64) {
        int a = bid >> 4;
        const float* in = (a == 0) ? w0 : (a == 1) ? w1 : (a == 2) ? w2 : w3;
        ushort* out = (a == 0) ? o0 : (a == 1) ? o1 : (a == 2) ? o2 : o3;
        cvt_body(in, out, bid & 15);
    } else {
        int b = bid - 64;
        int which = (b >= GB_CVT);
        cvt_body(which ? xt : xu, which ? xbf_t : xbf_u, b - which * GB_CVT);
    }
}

// build one relation, 4-edge ILP (standalone, atomic-bound)
__global__ __launch_bounds__(256) void build1_ilp_kernel(
    const int* __restrict__ src, const int* __restrict__ dst,
    int* __restrict__ head, int2* __restrict__ entry) {
    build_body_ilp(src, dst, head, entry, blockIdx.x);
}

// standalone bf16 seg-mean
__global__ __launch_bounds__(256) void seg_only_kernel(
    const ushort* __restrict__ x, const int* __restrict__ head,
    const int2* __restrict__ entry, ushort* __restrict__ outbf) {
    seg_body(x, head, entry, outbf, blockIdx.x);
}

// fatG: gemm rel0 (MFMA-pipe-bound) || build rel1 ILP (atomic-pipe-bound).
// Build uses ILP so it keeps its atomic throughput despite LDS-capped occupancy.
__global__ __launch_bounds__(256) void fatG_kernel(
    const ushort* __restrict__ xbf_t, const ushort* __restrict__ nbf0,
    const ushort* __restrict__ wbf_ps, const ushort* __restrict__ wbf_pn,
    const float* __restrict__ b1ps, const float* __restrict__ b1pn,
    const float* __restrict__ w2ps, const float* __restrict__ w2bn,
    float* __restrict__ dself_t, float* __restrict__ scross_t,
    const int* __restrict__ s1, const int* __restrict__ d1,
    int* __restrict__ head_pb, int2* __restrict__ ent_pb) {
    int bid = blockIdx.x;
    if (bid < GB_G)
        gemm_body(xbf_t, nbf0, wbf_ps, wbf_pn, b1ps, b1pn, w2ps, w2bn,
                  dself_t, scross_t, bid);
    else
        build_body_ilp(s1, d1, head_pb, ent_pb, bid - GB_G);
}

// fatC: gemm rel1 || user-side scalar traversal (reads only earlier outputs)
__global__ __launch_bounds__(256) void fatC_kernel(
    const ushort* __restrict__ xbf_u, const ushort* __restrict__ nbf1,
    const ushort* __restrict__ wbf_bs, const ushort* __restrict__ wbf_bn,
    const float* __restrict__ b1bs, const float* __restrict__ b1bn,
    const float* __restrict__ w2bs, const float* __restrict__ w2pn,
    float* __restrict__ dself_u, float* __restrict__ scross_u,
    const float* __restrict__ scross_t,
    const int* __restrict__ head_pb, const int2* __restrict__ ent_pb,
    float* __restrict__ smean_u) {
    int bid = blockIdx.x;
    if (bid < GB_G) {
        gemm_body(xbf_u, nbf1, wbf_bs, wbf_bn, b1bs, b1bn, w2bs, w2pn,
                  dself_u, scross_u, bid);
    } else {
        int i = (bid - GB_G) * 256 + threadIdx.x;
        if (i < N_NODES) smean_u[i] = smean_body(scross_t, head_pb, ent_pb, i);
    }
}

// tail: tweet-side traversal (needs gemm1's scross_u) + assemble both outputs
__global__ __launch_bounds__(256) void tail_kernel(
    const float* __restrict__ dself_u, const float* __restrict__ smean_u,
    const float* __restrict__ dself_t, const float* __restrict__ scross_u,
    const int* __restrict__ head_posts, const int2* __restrict__ ent_posts,
    const float* __restrict__ b2bs, const float* __restrict__ b2bn,
    const float* __restrict__ b2ps, const float* __restrict__ b2pn,
    float* __restrict__ out) {
    int i = blockIdx.x * 256 + threadIdx.x;
    if (i >= N_NODES) return;
    out[N_NODES + i] = dself_t[i] + smean_body(scross_u, head_posts, ent_posts, i)
                       + b2ps[0] + b2pn[0];
    out[i] = dself_u[i] + smean_u[i] + b2bs[0] + b2bn[0];
}

// -------- f32 fallback kernels (small-ws safety) --------

__global__ __launch_bounds__(256) void cvtw_kernel(
    const float* __restrict__ w0, const float* __restrict__ w1,
    const float* __restrict__ w2, const float* __restrict__ w3,
    ushort* __restrict__ o0, ushort* __restrict__ o1,
    ushort* __restrict__ o2, ushort* __restrict__ o3) {
    int a = blockIdx.y;
    const float* in = (a == 0) ? w0 : (a == 1) ? w1 : (a == 2) ? w2 : w3;
    ushort* out = (a == 0) ? o0 : (a == 1) ? o1 : (a == 2) ? o2 : o3;
    cvt_body(in, out, blockIdx.x);
}

__global__ __launch_bounds__(256) void build_lists2_kernel(
    const int* __restrict__ s0, const int* __restrict__ d0,
    const int* __restrict__ s1, const int* __restrict__ d1,
    int* __restrict__ head2, int2* __restrict__ entry2) {
    const int rel = blockIdx.y;
    build_body(rel ? s1 : s0, rel ? d1 : d0, head2 + (size_t)rel * N_NODES,
               entry2 + (size_t)rel * N_EDGES, blockIdx.x);
}

__global__ __launch_bounds__(256) void seg_mean_f32_list_kernel(
    const float* __restrict__ x, const int* __restrict__ head,
    const int2* __restrict__ entry, ushort* __restrict__ outbf) {
    int idx = blockIdx.x * 256 + threadIdx.x;
    int node = idx >> 5;
    if (node >= N_NODES) return;
    int f = (idx & 31) << 2;
    float4 acc = make_float4(0.f, 0.f, 0.f, 0.f);
    int cnt = 0;
    int e = head[node];
    while (e >= 0) {
        int2 nd = entry[e];
        ++cnt;
        float4 v = *reinterpret_cast<const float4*>(&x[(size_t)nd.x * DIM + f]);
        acc.x += v.x; acc.y += v.y; acc.z += v.z; acc.w += v.w;
        e = nd.y;
    }
    float r = 1.0f / fmaxf((float)cnt, 1.0f);
    ushort4 u = make_ushort4(f2bf(acc.x * r), f2bf(acc.y * r),
                             f2bf(acc.z * r), f2bf(acc.w * r));
    *reinterpret_cast<ushort4*>(&outbf[node * DIM + f]) = u;
}

__global__ __launch_bounds__(256) void gemm_mfma_f32_kernel(
    const float* __restrict__ Xs, const ushort* __restrict__ Nm,
    const ushort* __restrict__ Wsbf, const ushort* __restrict__ Wnbf,
    const float* __restrict__ bs, const float* __restrict__ bn,
    const float* __restrict__ w2a, const float* __restrict__ w2b,
    float* __restrict__ dself, float* __restrict__ dcross) {
    __shared__ ushort sA[128 * 64];
    __shared__ ushort sB[128 * 64];
    __shared__ float pS[2][2][128];

    const int tid = threadIdx.x;
    const int lane = tid & 63;
    const int wid = tid >> 6;
    const int wr = wid >> 1, wc = wid & 1;
    const int lr = lane & 15, lg = lane >> 4;
    const int row0 = blockIdx.x * 128;

    f32x4 acc[4][4];
#pragma unroll
    for (int i = 0; i < 4; ++i)
#pragma unroll
        for (int j = 0; j < 4; ++j) acc[i][j] = (f32x4){0.f, 0.f, 0.f, 0.f};

    const int r = tid >> 1;
    const int hh = tid & 1;
    const int grow = row0 + r;
    const int swzr = (r & 7) << 4;

    for (int kb = 0; kb < 256; kb += 64) {
        const int kg = kb & 127;
        const bool self = (kb < 128);
        __syncthreads();
        if (self) {
            const float4* g = reinterpret_cast<const float4*>(Xs);
#pragma unroll
            for (int q = 0; q < 4; ++q) {
                float4 v0 = make_float4(0.f, 0.f, 0.f, 0.f), v1 = v0;
                if (grow < N_NODES) {
                    size_t bi = ((size_t)grow * DIM + kg + hh * 32 + q * 8) >> 2;
                    v0 = g[bi];
                    v1 = g[bi + 1];
                }
                union { ushort s[8]; uint4 v; } u;
                u.s[0] = f2bf(v0.x); u.s[1] = f2bf(v0.y);
                u.s[2] = f2bf(v0.z); u.s[3] = f2bf(v0.w);
                u.s[4] = f2bf(v1.x); u.s[5] = f2bf(v1.y);
                u.s[6] = f2bf(v1.z); u.s[7] = f2bf(v1.w);
                int byte = (hh * 64 + q * 16) ^ swzr;
                *reinterpret_cast<uint4*>(&sA[r * 64 + (byte >> 1)]) = u.v;
            }
        } else {
            const uint4* g = reinterpret_cast<const uint4*>(Nm);
#pragma unroll
            for (int q = 0; q < 4; ++q) {
                uint4 v = make_uint4(0, 0, 0, 0);
                if (grow < N_NODES)
                    v = g[((size_t)grow * DIM + kg + hh * 32 + q * 8) >> 3];
                int byte = (hh * 64 + q * 16) ^ swzr;
                *reinterpret_cast<uint4*>(&sA[r * 64 + (byte >> 1)]) = v;
            }
        }
        {
            const uint4* g = reinterpret_cast<const uint4*>(self ? Wsbf : Wnbf);
#pragma unroll
            for (int q = 0; q < 4; ++q) {
                uint4 v = g[(r * DIM + kg + hh * 32 + q * 8) >> 3];
                int byte = (hh * 64 + q * 16) ^ swzr;
                *reinterpret_cast<uint4*>(&sB[r * 64 + (byte >> 1)]) = v;
            }
        }
        __syncthreads();
#pragma unroll
        for (int ks = 0; ks < 2; ++ks) {
            short8 a[4], b[4];
#pragma unroll
            for (int fm = 0; fm < 4; ++fm) {
                int rr = wr * 64 + fm * 16 + lr;
                int byte = (ks * 64 + lg * 16) ^ ((rr & 7) << 4);
                a[fm] = *reinterpret_cast<const short8*>(&sA[rr * 64 + (byte >> 1)]);
            }
#pragma unroll
            for (int fn = 0; fn < 4; ++fn) {
                int cc = wc * 64 + fn * 16 + lr;
                int byte = (ks * 64 + lg * 16) ^ ((cc & 7) << 4);
                b[fn] = *reinterpret_cast<const short8*>(&sB[cc * 64 + (byte >> 1)]);
            }
#pragma unroll
            for (int fm = 0; fm < 4; ++fm)
#pragma unroll
                for (int fn = 0; fn < 4; ++fn)
                    acc[fm][fn] = __builtin_amdgcn_mfma_f32_16x16x32_bf16(
                        a[fm], b[fn], acc[fm][fn], 0, 0, 0);
        }
    }

    float bias[4], wa[4], wb[4];
#pragma unroll
    for (int fn = 0; fn < 4; ++fn) {
        int c = wc * 64 + fn * 16 + lr;
        bias[fn] = bs[c] + bn[c];
        wa[fn] = w2a[c];
        wb[fn] = w2b[c];
    }
#pragma unroll
    for (int fm = 0; fm < 4; ++fm) {
#pragma unroll
        for (int reg = 0; reg < 4; ++reg) {
            float pa = 0.f, pb = 0.f;
#pragma unroll
            for (int fn = 0; fn < 4; ++fn) {
                float h = fmaxf(acc[fm][fn][reg] + bias[fn], 0.f);
                pa = fmaf(h, wa[fn], pa);
                pb = fmaf(h, wb[fn], pb);
            }
#pragma unroll
            for (int m = 1; m < 16; m <<= 1) {
                pa += __shfl_xor(pa, m);
                pb += __shfl_xor(pb, m);
            }
            if (lr == 0) {
                int rloc = wr * 64 + fm * 16 + lg * 4 + reg;
                pS[wc][0][rloc] = pa;
                pS[wc][1][rloc] = pb;
            }
        }
    }
    __syncthreads();
    if (tid < 128) {
        int go = row0 + tid;
        if (go < N_NODES) {
            dself[go] = pS[0][0][tid] + pS[1][0][tid];
            dcross[go] = pS[0][1][tid] + pS[1][1][tid];
        }
    }
}

__global__ __launch_bounds__(256) void scalar_finalize_kernel(
    const float* __restrict__ dself_u, const float* __restrict__ dself_t,
    const float* __restrict__ scross_u, const float* __restrict__ scross_t,
    const int* __restrict__ head2, const int2* __restrict__ entry2,
    const float* __restrict__ b2bs, const float* __restrict__ b2bn,
    const float* __restrict__ b2ps, const float* __restrict__ b2pn,
    float* __restrict__ out) {
    int i = blockIdx.x * 256 + threadIdx.x;
    if (i >= N_NODES) return;
    out[N_NODES + i] = dself_t[i] + smean_body(scross_u, head2, entry2, i)
                       + b2ps[0] + b2pn[0];
    out[i] = dself_u[i] + smean_body(scross_t, head2 + N_NODES, entry2 + N_EDGES, i)
             + b2bs[0] + b2bn[0];
}

// ===================================================================================

extern "C" void kernel_launch(void* const* d_in, const int* in_sizes, int n_in,
                              void* d_out, int out_size, void* d_ws, size_t ws_size,
                              hipStream_t stream) {
    const float* x_user  = (const float*)d_in[0];
    const float* x_tweet = (const float*)d_in[1];
    const float* w1ps = (const float*)d_in[2];  const float* b1ps = (const float*)d_in[3];
    const float* w1pn = (const float*)d_in[4];  const float* b1pn = (const float*)d_in[5];
    const float* w1bs = (const float*)d_in[6];  const float* b1bs = (const float*)d_in[7];
    const float* w1bn = (const float*)d_in[8];  const float* b1bn = (const float*)d_in[9];
    const float* w2ps = (const float*)d_in[10]; const float* b2ps = (const float*)d_in[11];
    const float* w2pn = (const float*)d_in[12]; const float* b2pn = (const float*)d_in[13];
    const float* w2bs = (const float*)d_in[14]; const float* b2bs = (const float*)d_in[15];
    const float* w2bn = (const float*)d_in[16]; const float* b2bn = (const float*)d_in[17];
    const int* src_posts = (const int*)d_in[18];
    const int* dst_posts = (const int*)d_in[19];
    const int* src_pb    = (const int*)d_in[20];
    const int* dst_pb    = (const int*)d_in[21];
    float* out = (float*)d_out;

    // ---- workspace layout (16B aligned regions) ----
    char* wsb = (char*)d_ws;
    ushort* nbf0    = (ushort*)wsb;   wsb += (size_t)N_NODES * DIM * 2;      // 25.6 MB
    int* head2      = (int*)wsb;      wsb += (size_t)2 * N_NODES * 4;        //  0.8 MB
    int2* entry2    = (int2*)wsb;     wsb += (size_t)2 * N_EDGES * 8;        //  8.0 MB
    ushort* wbf_ps  = (ushort*)wsb;   wsb += (size_t)DIM * DIM * 2;
    ushort* wbf_pn  = (ushort*)wsb;   wsb += (size_t)DIM * DIM * 2;
    ushort* wbf_bs  = (ushort*)wsb;   wsb += (size_t)DIM * DIM * 2;
    ushort* wbf_bn  = (ushort*)wsb;   wsb += (size_t)DIM * DIM * 2;
    float* dself_t  = (float*)wsb;    wsb += (size_t)N_NODES * 4;
    float* scross_t = (float*)wsb;    wsb += (size_t)N_NODES * 4;
    float* dself_u  = (float*)wsb;    wsb += (size_t)N_NODES * 4;
    float* scross_u = (float*)wsb;    wsb += (size_t)N_NODES * 4;
    float* smean_u  = (float*)wsb;    wsb += (size_t)N_NODES * 4;
    ushort* nbf1    = (ushort*)wsb;   wsb += (size_t)N_NODES * DIM * 2;      // 25.6 MB
    ushort* xbf_u   = (ushort*)wsb;   wsb += (size_t)N_NODES * DIM * 2;      // 25.6 MB
    ushort* xbf_t   = (ushort*)wsb;   wsb += (size_t)N_NODES * DIM * 2;      // 25.6 MB
    const bool use_bf = ((size_t)(wsb - (char*)d_ws) <= ws_size);

    int* head_posts = head2;
    int* head_pb    = head2 + N_NODES;
    int2* ent_posts = entry2;
    int2* ent_pb    = entry2 + N_EDGES;

    hipMemsetAsync(head2, 0xFF, (size_t)2 * N_NODES * sizeof(int), stream);

    if (!use_bf) {
        cvtw_kernel<<<dim3(16, 4), 256, 0, stream>>>(w1ps, w1pn, w1bs, w1bn,
                                                     wbf_ps, wbf_pn, wbf_bs, wbf_bn);
        build_lists2_kernel<<<dim3(GB_E, 2), 256, 0, stream>>>(
            src_posts, dst_posts, src_pb, dst_pb, head2, entry2);
        seg_mean_f32_list_kernel<<<(N_NODES * 32 + 255) / 256, 256, 0, stream>>>(
            x_user, head_posts, ent_posts, nbf0);
        gemm_mfma_f32_kernel<<<GB_G, 256, 0, stream>>>(x_tweet, nbf0, wbf_ps, wbf_pn,
                                                       b1ps, b1pn, w2ps, w2bn,
                                                       dself_t, scross_t);
        seg_mean_f32_list_kernel<<<(N_NODES * 32 + 255) / 256, 256, 0, stream>>>(
            x_tweet, head_pb, ent_pb, nbf0);
        gemm_mfma_f32_kernel<<<GB_G, 256, 0, stream>>>(x_user, nbf0, wbf_bs, wbf_bn,
                                                       b1bs, b1bn, w2bs, w2pn,
                                                       dself_u, scross_u);
        scalar_finalize_kernel<<<GB_N, 256, 0, stream>>>(dself_u, dself_t,
                                                         scross_u, scross_t,
                                                         head2, entry2,
                                                         b2bs, b2bn, b2ps, b2pn, out);
        return;
    }

    // -------- bf16 fast path --------
    // K1: pure-BW conversions (no atomics co-resident)
    cvt_fat_kernel<<<64 + 2 * GB_CVT, 256, 0, stream>>>(
        w1ps, w1pn, w1bs, w1bn, wbf_ps, wbf_pn, wbf_bs, wbf_bn,
        x_user, x_tweet, xbf_u, xbf_t);

    // K2: build rel0 alone, 4-edge ILP (atomic-bound)
    build1_ilp_kernel<<<GB_EI, 256, 0, stream>>>(src_posts, dst_posts,
                                                 head_posts, ent_posts);

    // K3: seg0 standalone (full-occupancy gather)
    seg_only_kernel<<<GB_SEG, 256, 0, stream>>>(xbf_u, head_posts, ent_posts, nbf0);

    // K4: gemm rel0 (MFMA pipe) || build rel1 ILP (atomic pipe)
    fatG_kernel<<<GB_G + GB_EI, 256, 0, stream>>>(
        xbf_t, nbf0, wbf_ps, wbf_pn, b1ps, b1pn, w2ps, w2bn,
        dself_t, scross_t, src_pb, dst_pb, head_pb, ent_pb);

    // K5: seg1 standalone
    seg_only_kernel<<<GB_SEG, 256, 0, stream>>>(xbf_t, head_pb, ent_pb, nbf1);

    // K6: gemm rel1 || user-side scalar traversal
    fatC_kernel<<<GB_G + GB_N, 256, 0, stream>>>(
        xbf_u, nbf1, wbf_bs, wbf_bn, b1bs, b1bn, w2bs, w2pn,
        dself_u, scross_u, scross_t, head_pb, ent_pb, smean_u);

    // K7: tweet-side traversal + output assembly
    tail_kernel<<<GB_N, 256, 0, stream>>>(dself_u, smean_u, dself_t, scross_u,
                                          head_posts, ent_posts,
                                          b2bs, b2bn, b2ps, b2pn, out);
}

// Round 11
// 187.833 us; speedup vs baseline: 1.1790x; 1.0514x over previous
//
#include <hip/hip_runtime.h>

#define N_NODES 100000
#define N_EDGES 500000
#define DIM 128
#define GB_E 1954      // ceil(E/256)
#define GB_EI 489      // ceil(E/1024) — 4 edges per thread (ILP build)
#define GB_N 391       // ceil(N/256)
#define GB_CVT 12500   // N*DIM/1024 per feature matrix
#define GB_G 782       // ceil(N/128) gemm tiles
#define GB_SEG 6250    // N*16/256 seg-mean blocks

typedef __attribute__((ext_vector_type(8))) short short8;   // 8 bf16 = 4 VGPRs
typedef __attribute__((ext_vector_type(4))) float f32x4;

__device__ __forceinline__ ushort f2bf(float f) {
    unsigned u = __float_as_uint(f);
    u += 0x7FFF + ((u >> 16) & 1);   // round-to-nearest-even
    return (ushort)(u >> 16);
}
__device__ __forceinline__ float bf2f(ushort s) {
    return __uint_as_float(((unsigned)s) << 16);
}

// ================= device bodies ====================================================

// 1-edge/thread build (fallback path)
__device__ __forceinline__ void build_body(const int* __restrict__ src,
                                           const int* __restrict__ dst,
                                           int* __restrict__ head,
                                           int2* __restrict__ entry, int bid) {
    int e = bid * 256 + threadIdx.x;
    if (e < N_EDGES) {
        int d = dst[e];
        int old = atomicExch(&head[d], e);
        entry[e] = make_int2(src[e], old);
    }
}

// 4-edge/thread ILP build: 4 independent atomicExch in flight per lane
__device__ __forceinline__ void build_body_ilp(const int* __restrict__ src,
                                               const int* __restrict__ dst,
                                               int* __restrict__ head,
                                               int2* __restrict__ entry, int bid) {
    int base = bid * 1024 + threadIdx.x;
    int e[4], d[4], s[4], old[4];
    bool ok[4];
#pragma unroll
    for (int k = 0; k < 4; ++k) {
        e[k] = base + k * 256;
        ok[k] = (e[k] < N_EDGES);
        d[k] = ok[k] ? dst[e[k]] : 0;
        s[k] = ok[k] ? src[e[k]] : 0;
    }
#pragma unroll
    for (int k = 0; k < 4; ++k)
        if (ok[k]) old[k] = atomicExch(&head[d[k]], e[k]);
#pragma unroll
    for (int k = 0; k < 4; ++k)
        if (ok[k]) entry[e[k]] = make_int2(s[k], old[k]);
}

__device__ __forceinline__ void cvt_body(const float* __restrict__ in,
                                         ushort* __restrict__ out, int bid) {
    int i = (bid * 256 + threadIdx.x) * 4;
    float4 v = *reinterpret_cast<const float4*>(&in[i]);
    ushort4 u = make_ushort4(f2bf(v.x), f2bf(v.y), f2bf(v.z), f2bf(v.w));
    *reinterpret_cast<ushort4*>(&out[i]) = u;
}

// bf16 seg-mean: 16 lanes/node, each lane owns 8 feats (16B loads)
__device__ __forceinline__ void seg_body(const ushort* __restrict__ x,
                                         const int* __restrict__ head,
                                         const int2* __restrict__ entry,
                                         ushort* __restrict__ outbf, int bid) {
    int idx = bid * 256 + threadIdx.x;
    int node = idx >> 4;
    if (node >= N_NODES) return;
    int f = (idx & 15) << 3;
    float acc[8];
#pragma unroll
    for (int j = 0; j < 8; ++j) acc[j] = 0.f;
    int cnt = 0;
    int e = head[node];
    while (e >= 0) {
        int2 nd = entry[e];   // dependent 8B load, broadcast within 16-lane group
        ++cnt;
        short8 v = *reinterpret_cast<const short8*>(&x[(size_t)nd.x * DIM + f]);
#pragma unroll
        for (int j = 0; j < 8; ++j) acc[j] += bf2f((ushort)v[j]);
        e = nd.y;
    }
    float r = 1.0f / fmaxf((float)cnt, 1.0f);
    union { ushort s[8]; uint4 v; } u;
#pragma unroll
    for (int j = 0; j < 8; ++j) u.s[j] = f2bf(acc[j] * r);
    *reinterpret_cast<uint4*>(&outbf[(size_t)node * DIM + f]) = u.v;
}

__device__ __forceinline__ float smean_body(const float* __restrict__ sval,
                                            const int* __restrict__ head,
                                            const int2* __restrict__ entry, int node) {
    float a = 0.f;
    int cnt = 0;
    int e = head[node];
    while (e >= 0) {
        int2 nd = entry[e];
        ++cnt;
        a += sval[nd.x];
        e = nd.y;
    }
    return a / fmaxf((float)cnt, 1.0f);
}

// fused layer-1 MFMA GEMM + layer-2 dots. h = relu(Xs@Ws.T+bs + Nm@Wn.T+bn);
// dself=h·w2a, dcross=h·w2b. 128x128 tile, 4 waves, K=256, BK=64, XOR-swizzled LDS.
__device__ __forceinline__ void gemm_body(
    const ushort* __restrict__ Xsbf, const ushort* __restrict__ Nm,
    const ushort* __restrict__ Wsbf, const ushort* __restrict__ Wnbf,
    const float* __restrict__ bs, const float* __restrict__ bn,
    const float* __restrict__ w2a, const float* __restrict__ w2b,
    float* __restrict__ dself, float* __restrict__ dcross, int blk) {
    __shared__ ushort sA[128 * 64];
    __shared__ ushort sB[128 * 64];
    __shared__ float pS[2][2][128];

    const int tid = threadIdx.x;
    const int lane = tid & 63;
    const int wid = tid >> 6;
    const int wr = wid >> 1, wc = wid & 1;
    const int lr = lane & 15, lg = lane >> 4;
    const int row0 = blk * 128;

    f32x4 acc[4][4];
#pragma unroll
    for (int i = 0; i < 4; ++i)
#pragma unroll
        for (int j = 0; j < 4; ++j) acc[i][j] = (f32x4){0.f, 0.f, 0.f, 0.f};

    const int r = tid >> 1;
    const int hh = tid & 1;
    const int grow = row0 + r;
    const int swzr = (r & 7) << 4;

    for (int kb = 0; kb < 256; kb += 64) {
        const int kg = kb & 127;
        const bool self = (kb < 128);
        __syncthreads();
        {
            const uint4* g = reinterpret_cast<const uint4*>(self ? Xsbf : Nm);
#pragma unroll
            for (int q = 0; q < 4; ++q) {
                uint4 v = make_uint4(0, 0, 0, 0);
                if (grow < N_NODES)
                    v = g[((size_t)grow * DIM + kg + hh * 32 + q * 8) >> 3];
                int byte = (hh * 64 + q * 16) ^ swzr;
                *reinterpret_cast<uint4*>(&sA[r * 64 + (byte >> 1)]) = v;
            }
        }
        {
            const uint4* g = reinterpret_cast<const uint4*>(self ? Wsbf : Wnbf);
#pragma unroll
            for (int q = 0; q < 4; ++q) {
                uint4 v = g[(r * DIM + kg + hh * 32 + q * 8) >> 3];
                int byte = (hh * 64 + q * 16) ^ swzr;
                *reinterpret_cast<uint4*>(&sB[r * 64 + (byte >> 1)]) = v;
            }
        }
        __syncthreads();
#pragma unroll
        for (int ks = 0; ks < 2; ++ks) {
            short8 a[4], b[4];
#pragma unroll
            for (int fm = 0; fm < 4; ++fm) {
                int rr = wr * 64 + fm * 16 + lr;
                int byte = (ks * 64 + lg * 16) ^ ((rr & 7) << 4);
                a[fm] = *reinterpret_cast<const short8*>(&sA[rr * 64 + (byte >> 1)]);
            }
#pragma unroll
            for (int fn = 0; fn < 4; ++fn) {
                int cc = wc * 64 + fn * 16 + lr;
                int byte = (ks * 64 + lg * 16) ^ ((cc & 7) << 4);
                b[fn] = *reinterpret_cast<const short8*>(&sB[cc * 64 + (byte >> 1)]);
            }
#pragma unroll
            for (int fm = 0; fm < 4; ++fm)
#pragma unroll
                for (int fn = 0; fn < 4; ++fn)
                    acc[fm][fn] = __builtin_amdgcn_mfma_f32_16x16x32_bf16(
                        a[fm], b[fn], acc[fm][fn], 0, 0, 0);
        }
    }

    float bias[4], wa[4], wb[4];
#pragma unroll
    for (int fn = 0; fn < 4; ++fn) {
        int c = wc * 64 + fn * 16 + lr;
        bias[fn] = bs[c] + bn[c];
        wa[fn] = w2a[c];
        wb[fn] = w2b[c];
    }
#pragma unroll
    for (int fm = 0; fm < 4; ++fm) {
#pragma unroll
        for (int reg = 0; reg < 4; ++reg) {
            float pa = 0.f, pb = 0.f;
#pragma unroll
            for (int fn = 0; fn < 4; ++fn) {
                float h = fmaxf(acc[fm][fn][reg] + bias[fn], 0.f);
                pa = fmaf(h, wa[fn], pa);
                pb = fmaf(h, wb[fn], pb);
            }
#pragma unroll
            for (int m = 1; m < 16; m <<= 1) {
                pa += __shfl_xor(pa, m);
                pb += __shfl_xor(pb, m);
            }
            if (lr == 0) {
                int rloc = wr * 64 + fm * 16 + lg * 4 + reg;   // C/D row=(lane>>4)*4+reg
                pS[wc][0][rloc] = pa;
                pS[wc][1][rloc] = pb;
            }
        }
    }
    __syncthreads();
    if (tid < 128) {
        int go = row0 + tid;
        if (go < N_NODES) {
            dself[go] = pS[0][0][tid] + pS[1][0][tid];
            dcross[go] = pS[0][1][tid] + pS[1][1][tid];
        }
    }
}

// ================= kernels ==========================================================

// cvt-fat: weight cvt (64 blocks) + both feature cvts (pure BW, no atomics)
__global__ __launch_bounds__(256) void cvt_fat_kernel(
    const float* __restrict__ w0, const float* __restrict__ w1,
    const float* __restrict__ w2, const float* __restrict__ w3,
    ushort* __restrict__ o0, ushort* __restrict__ o1,
    ushort* __restrict__ o2, ushort* __restrict__ o3,
    const float* __restrict__ xu, const float* __restrict__ xt,
    ushort* __restrict__ xbf_u, ushort* __restrict__ xbf_t) {
    int bid = blockIdx.x;
    if (bid < 64) {
        int a = bid >> 4;
        const float* in = (a == 0) ? w0 : (a == 1) ? w1 : (a == 2) ? w2 : w3;
        ushort* out = (a == 0) ? o0 : (a == 1) ? o1 : (a == 2) ? o2 : o3;
        cvt_body(in, out, bid & 15);
    } else {
        int b = bid - 64;
        int which = (b >= GB_CVT);
        cvt_body(which ? xt : xu, which ? xbf_t : xbf_u, b - which * GB_CVT);
    }
}

// buildBoth: both relations, 4-edge ILP, one dispatch (atomic-bound, nothing else)
__global__ __launch_bounds__(256) void build2_ilp_kernel(
    const int* __restrict__ s0, const int* __restrict__ d0,
    const int* __restrict__ s1, const int* __restrict__ d1,
    int* __restrict__ head2, int2* __restrict__ entry2) {
    const int rel = blockIdx.y;
    build_body_ilp(rel ? s1 : s0, rel ? d1 : d0, head2 + (size_t)rel * N_NODES,
                   entry2 + (size_t)rel * N_EDGES, blockIdx.x);
}

// segBoth: both relations' neighbor means, one dispatch (gather/BW-bound, no LDS)
__global__ __launch_bounds__(256) void seg2_kernel(
    const ushort* __restrict__ xbf_u, const int* __restrict__ head_posts,
    const int2* __restrict__ ent_posts, ushort* __restrict__ nbf0,
    const ushort* __restrict__ xbf_t, const int* __restrict__ head_pb,
    const int2* __restrict__ ent_pb, ushort* __restrict__ nbf1) {
    if (blockIdx.y == 0)
        seg_body(xbf_u, head_posts, ent_posts, nbf0, blockIdx.x);
    else
        seg_body(xbf_t, head_pb, ent_pb, nbf1, blockIdx.x);
}

// gemmBoth: both relations' fused L1-GEMM+L2-dots, one dispatch (1564 blocks
// doubles co-resident tiles for the latency-bound MFMA phase)
__global__ __launch_bounds__(256) void gemm2_kernel(
    const ushort* __restrict__ xbf_t, const ushort* __restrict__ nbf0,
    const ushort* __restrict__ wbf_ps, const ushort* __restrict__ wbf_pn,
    const float* __restrict__ b1ps, const float* __restrict__ b1pn,
    const float* __restrict__ w2ps, const float* __restrict__ w2bn,
    float* __restrict__ dself_t, float* __restrict__ scross_t,
    const ushort* __restrict__ xbf_u, const ushort* __restrict__ nbf1,
    const ushort* __restrict__ wbf_bs, const ushort* __restrict__ wbf_bn,
    const float* __restrict__ b1bs, const float* __restrict__ b1bn,
    const float* __restrict__ w2bs, const float* __restrict__ w2pn,
    float* __restrict__ dself_u, float* __restrict__ scross_u) {
    if (blockIdx.y == 0)
        gemm_body(xbf_t, nbf0, wbf_ps, wbf_pn, b1ps, b1pn, w2ps, w2bn,
                  dself_t, scross_t, blockIdx.x);
    else
        gemm_body(xbf_u, nbf1, wbf_bs, wbf_bn, b1bs, b1bn, w2bs, w2pn,
                  dself_u, scross_u, blockIdx.x);
}

// finalize: both layer-2 scalar traversals + output assembly
__global__ __launch_bounds__(256) void scalar_finalize_kernel(
    const float* __restrict__ dself_u, const float* __restrict__ dself_t,
    const float* __restrict__ scross_u, const float* __restrict__ scross_t,
    const int* __restrict__ head2, const int2* __restrict__ entry2,
    const float* __restrict__ b2bs, const float* __restrict__ b2bn,
    const float* __restrict__ b2ps, const float* __restrict__ b2pn,
    float* __restrict__ out) {
    int i = blockIdx.x * 256 + threadIdx.x;
    if (i >= N_NODES) return;
    out[N_NODES + i] = dself_t[i] + smean_body(scross_u, head2, entry2, i)
                       + b2ps[0] + b2pn[0];
    out[i] = dself_u[i] + smean_body(scross_t, head2 + N_NODES, entry2 + N_EDGES, i)
             + b2bs[0] + b2bn[0];
}

// -------- f32 fallback kernels (small-ws safety) --------

__global__ __launch_bounds__(256) void cvtw_kernel(
    const float* __restrict__ w0, const float* __restrict__ w1,
    const float* __restrict__ w2, const float* __restrict__ w3,
    ushort* __restrict__ o0, ushort* __restrict__ o1,
    ushort* __restrict__ o2, ushort* __restrict__ o3) {
    int a = blockIdx.y;
    const float* in = (a == 0) ? w0 : (a == 1) ? w1 : (a == 2) ? w2 : w3;
    ushort* out = (a == 0) ? o0 : (a == 1) ? o1 : (a == 2) ? o2 : o3;
    cvt_body(in, out, blockIdx.x);
}

__global__ __launch_bounds__(256) void build_lists2_kernel(
    const int* __restrict__ s0, const int* __restrict__ d0,
    const int* __restrict__ s1, const int* __restrict__ d1,
    int* __restrict__ head2, int2* __restrict__ entry2) {
    const int rel = blockIdx.y;
    build_body(rel ? s1 : s0, rel ? d1 : d0, head2 + (size_t)rel * N_NODES,
               entry2 + (size_t)rel * N_EDGES, blockIdx.x);
}

__global__ __launch_bounds__(256) void seg_mean_f32_list_kernel(
    const float* __restrict__ x, const int* __restrict__ head,
    const int2* __restrict__ entry, ushort* __restrict__ outbf) {
    int idx = blockIdx.x * 256 + threadIdx.x;
    int node = idx >> 5;
    if (node >= N_NODES) return;
    int f = (idx & 31) << 2;
    float4 acc = make_float4(0.f, 0.f, 0.f, 0.f);
    int cnt = 0;
    int e = head[node];
    while (e >= 0) {
        int2 nd = entry[e];
        ++cnt;
        float4 v = *reinterpret_cast<const float4*>(&x[(size_t)nd.x * DIM + f]);
        acc.x += v.x; acc.y += v.y; acc.z += v.z; acc.w += v.w;
        e = nd.y;
    }
    float r = 1.0f / fmaxf((float)cnt, 1.0f);
    ushort4 u = make_ushort4(f2bf(acc.x * r), f2bf(acc.y * r),
                             f2bf(acc.z * r), f2bf(acc.w * r));
    *reinterpret_cast<ushort4*>(&outbf[node * DIM + f]) = u;
}

__global__ __launch_bounds__(256) void gemm_mfma_f32_kernel(
    const float* __restrict__ Xs, const ushort* __restrict__ Nm,
    const ushort* __restrict__ Wsbf, const ushort* __restrict__ Wnbf,
    const float* __restrict__ bs, const float* __restrict__ bn,
    const float* __restrict__ w2a, const float* __restrict__ w2b,
    float* __restrict__ dself, float* __restrict__ dcross) {
    __shared__ ushort sA[128 * 64];
    __shared__ ushort sB[128 * 64];
    __shared__ float pS[2][2][128];

    const int tid = threadIdx.x;
    const int lane = tid & 63;
    const int wid = tid >> 6;
    const int wr = wid >> 1, wc = wid & 1;
    const int lr = lane & 15, lg = lane >> 4;
    const int row0 = blockIdx.x * 128;

    f32x4 acc[4][4];
#pragma unroll
    for (int i = 0; i < 4; ++i)
#pragma unroll
        for (int j = 0; j < 4; ++j) acc[i][j] = (f32x4){0.f, 0.f, 0.f, 0.f};

    const int r = tid >> 1;
    const int hh = tid & 1;
    const int grow = row0 + r;
    const int swzr = (r & 7) << 4;

    for (int kb = 0; kb < 256; kb += 64) {
        const int kg = kb & 127;
        const bool self = (kb < 128);
        __syncthreads();
        if (self) {
            const float4* g = reinterpret_cast<const float4*>(Xs);
#pragma unroll
            for (int q = 0; q < 4; ++q) {
                float4 v0 = make_float4(0.f, 0.f, 0.f, 0.f), v1 = v0;
                if (grow < N_NODES) {
                    size_t bi = ((size_t)grow * DIM + kg + hh * 32 + q * 8) >> 2;
                    v0 = g[bi];
                    v1 = g[bi + 1];
                }
                union { ushort s[8]; uint4 v; } u;
                u.s[0] = f2bf(v0.x); u.s[1] = f2bf(v0.y);
                u.s[2] = f2bf(v0.z); u.s[3] = f2bf(v0.w);
                u.s[4] = f2bf(v1.x); u.s[5] = f2bf(v1.y);
                u.s[6] = f2bf(v1.z); u.s[7] = f2bf(v1.w);
                int byte = (hh * 64 + q * 16) ^ swzr;
                *reinterpret_cast<uint4*>(&sA[r * 64 + (byte >> 1)]) = u.v;
            }
        } else {
            const uint4* g = reinterpret_cast<const uint4*>(Nm);
#pragma unroll
            for (int q = 0; q < 4; ++q) {
                uint4 v = make_uint4(0, 0, 0, 0);
                if (grow < N_NODES)
                    v = g[((size_t)grow * DIM + kg + hh * 32 + q * 8) >> 3];
                int byte = (hh * 64 + q * 16) ^ swzr;
                *reinterpret_cast<uint4*>(&sA[r * 64 + (byte >> 1)]) = v;
            }
        }
        {
            const uint4* g = reinterpret_cast<const uint4*>(self ? Wsbf : Wnbf);
#pragma unroll
            for (int q = 0; q < 4; ++q) {
                uint4 v = g[(r * DIM + kg + hh * 32 + q * 8) >> 3];
                int byte = (hh * 64 + q * 16) ^ swzr;
                *reinterpret_cast<uint4*>(&sB[r * 64 + (byte >> 1)]) = v;
            }
        }
        __syncthreads();
#pragma unroll
        for (int ks = 0; ks < 2; ++ks) {
            short8 a[4], b[4];
#pragma unroll
            for (int fm = 0; fm < 4; ++fm) {
                int rr = wr * 64 + fm * 16 + lr;
                int byte = (ks * 64 + lg * 16) ^ ((rr & 7) << 4);
                a[fm] = *reinterpret_cast<const short8*>(&sA[rr * 64 + (byte >> 1)]);
            }
#pragma unroll
            for (int fn = 0; fn < 4; ++fn) {
                int cc = wc * 64 + fn * 16 + lr;
                int byte = (ks * 64 + lg * 16) ^ ((cc & 7) << 4);
                b[fn] = *reinterpret_cast<const short8*>(&sB[cc * 64 + (byte >> 1)]);
            }
#pragma unroll
            for (int fm = 0; fm < 4; ++fm)
#pragma unroll
                for (int fn = 0; fn < 4; ++fn)
                    acc[fm][fn] = __builtin_amdgcn_mfma_f32_16x16x32_bf16(
                        a[fm], b[fn], acc[fm][fn], 0, 0, 0);
        }
    }

    float bias[4], wa[4], wb[4];
#pragma unroll
    for (int fn = 0; fn < 4; ++fn) {
        int c = wc * 64 + fn * 16 + lr;
        bias[fn] = bs[c] + bn[c];
        wa[fn] = w2a[c];
        wb[fn] = w2b[c];
    }
#pragma unroll
    for (int fm = 0; fm < 4; ++fm) {
#pragma unroll
        for (int reg = 0; reg < 4; ++reg) {
            float pa = 0.f, pb = 0.f;
#pragma unroll
            for (int fn = 0; fn < 4; ++fn) {
                float h = fmaxf(acc[fm][fn][reg] + bias[fn], 0.f);
                pa = fmaf(h, wa[fn], pa);
                pb = fmaf(h, wb[fn], pb);
            }
#pragma unroll
            for (int m = 1; m < 16; m <<= 1) {
                pa += __shfl_xor(pa, m);
                pb += __shfl_xor(pb, m);
            }
            if (lr == 0) {
                int rloc = wr * 64 + fm * 16 + lg * 4 + reg;
                pS[wc][0][rloc] = pa;
                pS[wc][1][rloc] = pb;
            }
        }
    }
    __syncthreads();
    if (tid < 128) {
        int go = row0 + tid;
        if (go < N_NODES) {
            dself[go] = pS[0][0][tid] + pS[1][0][tid];
            dcross[go] = pS[0][1][tid] + pS[1][1][tid];
        }
    }
}

// ===================================================================================

extern "C" void kernel_launch(void* const* d_in, const int* in_sizes, int n_in,
                              void* d_out, int out_size, void* d_ws, size_t ws_size,
                              hipStream_t stream) {
    const float* x_user  = (const float*)d_in[0];
    const float* x_tweet = (const float*)d_in[1];
    const float* w1ps = (const float*)d_in[2];  const float* b1ps = (const float*)d_in[3];
    const float* w1pn = (const float*)d_in[4];  const float* b1pn = (const float*)d_in[5];
    const float* w1bs = (const float*)d_in[6];  const float* b1bs = (const float*)d_in[7];
    const float* w1bn = (const float*)d_in[8];  const float* b1bn = (const float*)d_in[9];
    const float* w2ps = (const float*)d_in[10]; const float* b2ps = (const float*)d_in[11];
    const float* w2pn = (const float*)d_in[12]; const float* b2pn = (const float*)d_in[13];
    const float* w2bs = (const float*)d_in[14]; const float* b2bs = (const float*)d_in[15];
    const float* w2bn = (const float*)d_in[16]; const float* b2bn = (const float*)d_in[17];
    const int* src_posts = (const int*)d_in[18];
    const int* dst_posts = (const int*)d_in[19];
    const int* src_pb    = (const int*)d_in[20];
    const int* dst_pb    = (const int*)d_in[21];
    float* out = (float*)d_out;

    // ---- workspace layout (16B aligned regions) ----
    char* wsb = (char*)d_ws;
    ushort* nbf0    = (ushort*)wsb;   wsb += (size_t)N_NODES * DIM * 2;      // 25.6 MB
    int* head2      = (int*)wsb;      wsb += (size_t)2 * N_NODES * 4;        //  0.8 MB
    int2* entry2    = (int2*)wsb;     wsb += (size_t)2 * N_EDGES * 8;        //  8.0 MB
    ushort* wbf_ps  = (ushort*)wsb;   wsb += (size_t)DIM * DIM * 2;
    ushort* wbf_pn  = (ushort*)wsb;   wsb += (size_t)DIM * DIM * 2;
    ushort* wbf_bs  = (ushort*)wsb;   wsb += (size_t)DIM * DIM * 2;
    ushort* wbf_bn  = (ushort*)wsb;   wsb += (size_t)DIM * DIM * 2;
    float* dself_t  = (float*)wsb;    wsb += (size_t)N_NODES * 4;
    float* scross_t = (float*)wsb;    wsb += (size_t)N_NODES * 4;
    float* dself_u  = (float*)wsb;    wsb += (size_t)N_NODES * 4;
    float* scross_u = (float*)wsb;    wsb += (size_t)N_NODES * 4;
    float* smean_u  = (float*)wsb;    wsb += (size_t)N_NODES * 4;
    ushort* nbf1    = (ushort*)wsb;   wsb += (size_t)N_NODES * DIM * 2;      // 25.6 MB
    ushort* xbf_u   = (ushort*)wsb;   wsb += (size_t)N_NODES * DIM * 2;      // 25.6 MB
    ushort* xbf_t   = (ushort*)wsb;   wsb += (size_t)N_NODES * DIM * 2;      // 25.6 MB
    const bool use_bf = ((size_t)(wsb - (char*)d_ws) <= ws_size);

    int* head_posts = head2;
    int* head_pb    = head2 + N_NODES;
    int2* ent_posts = entry2;
    int2* ent_pb    = entry2 + N_EDGES;

    hipMemsetAsync(head2, 0xFF, (size_t)2 * N_NODES * sizeof(int), stream);

    if (!use_bf) {
        cvtw_kernel<<<dim3(16, 4), 256, 0, stream>>>(w1ps, w1pn, w1bs, w1bn,
                                                     wbf_ps, wbf_pn, wbf_bs, wbf_bn);
        build_lists2_kernel<<<dim3(GB_E, 2), 256, 0, stream>>>(
            src_posts, dst_posts, src_pb, dst_pb, head2, entry2);
        seg_mean_f32_list_kernel<<<(N_NODES * 32 + 255) / 256, 256, 0, stream>>>(
            x_user, head_posts, ent_posts, nbf0);
        gemm_mfma_f32_kernel<<<GB_G, 256, 0, stream>>>(x_tweet, nbf0, wbf_ps, wbf_pn,
                                                       b1ps, b1pn, w2ps, w2bn,
                                                       dself_t, scross_t);
        seg_mean_f32_list_kernel<<<(N_NODES * 32 + 255) / 256, 256, 0, stream>>>(
            x_tweet, head_pb, ent_pb, nbf0);
        gemm_mfma_f32_kernel<<<GB_G, 256, 0, stream>>>(x_user, nbf0, wbf_bs, wbf_bn,
                                                       b1bs, b1bn, w2bs, w2pn,
                                                       dself_u, scross_u);
        scalar_finalize_kernel<<<GB_N, 256, 0, stream>>>(dself_u, dself_t,
                                                         scross_u, scross_t,
                                                         head2, entry2,
                                                         b2bs, b2bn, b2ps, b2pn, out);
        return;
    }

    // -------- bf16 fast path: 5 phase-fused dispatches --------
    // K1: all dtype conversions (pure BW)
    cvt_fat_kernel<<<64 + 2 * GB_CVT, 256, 0, stream>>>(
        w1ps, w1pn, w1bs, w1bn, wbf_ps, wbf_pn, wbf_bs, wbf_bn,
        x_user, x_tweet, xbf_u, xbf_t);

    // K2: both adjacency builds, ILP-4 (atomic pipe, nothing else co-resident)
    build2_ilp_kernel<<<dim3(GB_EI, 2), 256, 0, stream>>>(
        src_posts, dst_posts, src_pb, dst_pb, head2, entry2);

    // K3: both neighbor-mean gathers (BW/latency, no LDS)
    seg2_kernel<<<dim3(GB_SEG, 2), 256, 0, stream>>>(
        xbf_u, head_posts, ent_posts, nbf0, xbf_t, head_pb, ent_pb, nbf1);

    // K4: both fused GEMMs (2x blocks fills the latency-bound MFMA phase)
    gemm2_kernel<<<dim3(GB_G, 2), 256, 0, stream>>>(
        xbf_t, nbf0, wbf_ps, wbf_pn, b1ps, b1pn, w2ps, w2bn, dself_t, scross_t,
        xbf_u, nbf1, wbf_bs, wbf_bn, b1bs, b1bn, w2bs, w2pn, dself_u, scross_u);

    // K5: both layer-2 traversals + output assembly
    scalar_finalize_kernel<<<GB_N, 256, 0, stream>>>(dself_u, dself_t,
                                                     scross_u, scross_t,
                                                     head2, entry2,
                                                     b2bs, b2bn, b2ps, b2pn, out);
}